// Round 11
// baseline (2077.554 us; speedup 1.0000x reference)
//
#include <hip/hip_runtime.h>
#include <cstdint>
#include <cstddef>

typedef unsigned int u32;
typedef unsigned short u16;
typedef __bf16 bf16x8 __attribute__((ext_vector_type(8)));
typedef float f32x4 __attribute__((ext_vector_type(4)));
typedef float f32x16 __attribute__((ext_vector_type(16)));
typedef int i32x4 __attribute__((ext_vector_type(4)));

#define DEV static __device__ __forceinline__

// ---------- helpers ----------
DEV float bf2f(u16 u) { u32 x = ((u32)u) << 16; return __builtin_bit_cast(float, x); }
DEV u16 f2bf(float f) {
  u32 u = __builtin_bit_cast(u32, f);
  u32 r = (u + 0x7fffu + ((u >> 16) & 1u)) >> 16;  // RNE
  return (u16)r;
}
DEV u32 pkbf(float a, float b) {
  __bf16 ba = (__bf16)a, bb = (__bf16)b;
  return (u32)__builtin_bit_cast(u16, ba) | ((u32)__builtin_bit_cast(u16, bb) << 16);
}
DEV u32 pk4i8(float a, float b, float c, float d) {
  return (u32)(unsigned char)(char)a | ((u32)(unsigned char)(char)b << 8) |
         ((u32)(unsigned char)(char)c << 16) | ((u32)(unsigned char)(char)d << 24);
}
DEV void bf8tof(const uint4 v, float* f) {
  f[0] = bf2f((u16)(v.x & 0xffffu)); f[1] = bf2f((u16)(v.x >> 16));
  f[2] = bf2f((u16)(v.y & 0xffffu)); f[3] = bf2f((u16)(v.y >> 16));
  f[4] = bf2f((u16)(v.z & 0xffffu)); f[5] = bf2f((u16)(v.z >> 16));
  f[6] = bf2f((u16)(v.w & 0xffffu)); f[7] = bf2f((u16)(v.w >> 16));
}
DEV uint4 f8tobf(const float* f) {
  uint4 r;
  r.x = (u32)f2bf(f[0]) | ((u32)f2bf(f[1]) << 16);
  r.y = (u32)f2bf(f[2]) | ((u32)f2bf(f[3]) << 16);
  r.z = (u32)f2bf(f[4]) | ((u32)f2bf(f[5]) << 16);
  r.w = (u32)f2bf(f[6]) | ((u32)f2bf(f[7]) << 16);
  return r;
}
DEV float sigmoidf_(float x) { return 1.f / (1.f + expf(-x)); }

DEV float wred_sum(float v) {
  #pragma unroll
  for (int m = 32; m; m >>= 1) v += __shfl_xor(v, m, 64);
  return v;
}
DEV float wred_max(float v) {
  #pragma unroll
  for (int m = 32; m; m >>= 1) v = fmaxf(v, __shfl_xor(v, m, 64));
  return v;
}
DEV float block_sum(float v, float* red, int nw) {
  v = wred_sum(v);
  int w = threadIdx.x >> 6, l = threadIdx.x & 63;
  if (l == 0) red[w] = v;
  __syncthreads();
  float t = red[0];
  for (int i = 1; i < nw; ++i) t += red[i];
  __syncthreads();
  return t;
}
DEV float block_max(float v, float* red, int nw) {
  v = wred_max(v);
  int w = threadIdx.x >> 6, l = threadIdx.x & 63;
  if (l == 0) red[w] = v;
  __syncthreads();
  float t = red[0];
  for (int i = 1; i < nw; ++i) t = fmaxf(t, red[i]);
  __syncthreads();
  return t;
}
DEV void gload16(const void* g, void* l) {
  __builtin_amdgcn_global_load_lds((const __attribute__((address_space(1))) void*)g,
                                   (__attribute__((address_space(3))) void*)l, 16, 0, 0);
}
DEV bf16x8 ldfrag(const u16* p) {
  uint4 u = *(const uint4*)p;
  return __builtin_bit_cast(bf16x8, u);
}

// ---------- constants ----------
#define BN_ 4
#define S_ 4096
#define HID_ 2048
#define NH_ 32
#define HD_ 64
#define INTER_ 8192
#define NBSEG_ 8
#define SEG_ 512
#define TOK_ 16384
#define CHROWS_ 4096   // MLP token-chunk rows
#define LDQ_ 6144      // fused qkv row stride

// ---------- elementwise / prep kernels ----------
__global__ __launch_bounds__(256) void castf2b(const float* __restrict__ a, u16* __restrict__ o) {
  size_t idx = ((size_t)blockIdx.x * 256 + threadIdx.x) * 4;
  float4 v = *(const float4*)(a + idx);
  float f[4] = {v.x, v.y, v.z, v.w};
  uint2 r;
  r.x = (u32)f2bf(f[0]) | ((u32)f2bf(f[1]) << 16);
  r.y = (u32)f2bf(f[2]) | ((u32)f2bf(f[3]) << 16);
  *(uint2*)(o + idx) = r;
}

__global__ __launch_bounds__(256) void absmean_part(const float* __restrict__ w, float* __restrict__ part) {
  __shared__ float red[4];
  size_t base = (size_t)blockIdx.x * 16384 + threadIdx.x * 4;
  float s = 0.f;
  #pragma unroll
  for (int i = 0; i < 16; ++i) {
    float4 v = *(const float4*)(w + base + (size_t)i * 1024);
    s += fabsf(v.x) + fabsf(v.y) + fabsf(v.z) + fabsf(v.w);
  }
  float t = block_sum(s, red, 4);
  if (threadIdx.x == 0) part[blockIdx.x] = t;
}

__global__ __launch_bounds__(256) void absmean_fin(const float* __restrict__ part, int n, float invN, float* __restrict__ outp) {
  __shared__ float red[4];
  float s = 0.f;
  for (int i = threadIdx.x; i < n; i += 256) s += part[i];
  float t = block_sum(s, red, 4);
  if (threadIdx.x == 0) outp[0] = t * invN + 1e-8f;
}

// ternary weights -> i8
__global__ __launch_bounds__(256) void ternarize_i8(const float* __restrict__ w, const float* __restrict__ wsp, char* __restrict__ o) {
  size_t idx = ((size_t)blockIdx.x * 256 + threadIdx.x) * 4;
  const float inv = 1.f / wsp[0];
  float4 v = *(const float4*)(w + idx);
  float q0 = rintf(fminf(fmaxf(v.x * inv, -1.f), 1.f));
  float q1 = rintf(fminf(fmaxf(v.y * inv, -1.f), 1.f));
  float q2 = rintf(fminf(fmaxf(v.z * inv, -1.f), 1.f));
  float q3 = rintf(fminf(fmaxf(v.w * inv, -1.f), 1.f));
  *(u32*)(o + idx) = pk4i8(q0, q1, q2, q3);
}

__global__ __launch_bounds__(256) void rmsnorm_cast(const float* __restrict__ x, const float* __restrict__ wn, u16* __restrict__ o) {
  __shared__ float red[4];
  const int r = blockIdx.x, tid = threadIdx.x;
  const float* xr = x + (size_t)r * HID_;
  float vx[8];
  #pragma unroll
  for (int i = 0; i < 2; ++i) {
    float4 t = *(const float4*)(xr + tid * 8 + i * 4);
    vx[i * 4 + 0] = t.x; vx[i * 4 + 1] = t.y; vx[i * 4 + 2] = t.z; vx[i * 4 + 3] = t.w;
  }
  float ss = 0.f;
  #pragma unroll
  for (int j = 0; j < 8; ++j) ss += vx[j] * vx[j];
  float tot = block_sum(ss, red, 4);
  float rstd = rsqrtf(tot * (1.f / HID_) + 1e-5f);
  float wv[8];
  #pragma unroll
  for (int i = 0; i < 2; ++i) {
    float4 t = *(const float4*)(wn + tid * 8 + i * 4);
    wv[i * 4 + 0] = t.x; wv[i * 4 + 1] = t.y; wv[i * 4 + 2] = t.z; wv[i * 4 + 3] = t.w;
  }
  float ov[8];
  #pragma unroll
  for (int j = 0; j < 8; ++j) ov[j] = vx[j] * rstd * wv[j];
  *(uint4*)(o + (size_t)r * HID_ + tid * 8) = f8tobf(ov);
}

// fused: x2 = x + rs1 * rmsnorm(sig(gate)*ao, w1); then xq(i8) = int8quant(rmsnorm(x2, w2))
__global__ __launch_bounds__(256) void resid1_rms2(const float* __restrict__ x, const u16* __restrict__ ao,
    const float* __restrict__ gatep, const float* __restrict__ w1, const float* __restrict__ rsp,
    const float* __restrict__ w2, float* __restrict__ x2, char* __restrict__ xq, float* __restrict__ xs1) {
  __shared__ float red[4];
  const int r = blockIdx.x, tid = threadIdx.x;
  const float g = sigmoidf_(gatep[0]);
  const float rs = rsp[0];
  uint4 av = *(const uint4*)(ao + (size_t)r * HID_ + tid * 8);
  float f[8]; bf8tof(av, f);
  float ss = 0.f;
  #pragma unroll
  for (int j = 0; j < 8; ++j) { f[j] *= g; ss += f[j] * f[j]; }
  float tot = block_sum(ss, red, 4);
  float rstd1 = rsqrtf(tot * (1.f / HID_) + 1e-5f);
  const float* xr = x + (size_t)r * HID_;
  float xv2[8];
  #pragma unroll
  for (int i = 0; i < 2; ++i) {
    float4 xv = *(const float4*)(xr + tid * 8 + i * 4);
    float4 wv = *(const float4*)(w1 + tid * 8 + i * 4);
    xv2[i * 4 + 0] = xv.x + rs * f[i * 4 + 0] * rstd1 * wv.x;
    xv2[i * 4 + 1] = xv.y + rs * f[i * 4 + 1] * rstd1 * wv.y;
    xv2[i * 4 + 2] = xv.z + rs * f[i * 4 + 2] * rstd1 * wv.z;
    xv2[i * 4 + 3] = xv.w + rs * f[i * 4 + 3] * rstd1 * wv.w;
  }
  float* o = x2 + (size_t)r * HID_;
  *(float4*)(o + tid * 8) = float4{xv2[0], xv2[1], xv2[2], xv2[3]};
  *(float4*)(o + tid * 8 + 4) = float4{xv2[4], xv2[5], xv2[6], xv2[7]};
  float ss2 = 0.f;
  #pragma unroll
  for (int j = 0; j < 8; ++j) ss2 += xv2[j] * xv2[j];
  float tot2 = block_sum(ss2, red, 4);
  float rstd2 = rsqrtf(tot2 * (1.f / HID_) + 1e-5f);
  float xn[8]; float mx = 0.f;
  #pragma unroll
  for (int i = 0; i < 2; ++i) {
    float4 wv = *(const float4*)(w2 + tid * 8 + i * 4);
    xn[i * 4 + 0] = xv2[i * 4 + 0] * rstd2 * wv.x;
    xn[i * 4 + 1] = xv2[i * 4 + 1] * rstd2 * wv.y;
    xn[i * 4 + 2] = xv2[i * 4 + 2] * rstd2 * wv.z;
    xn[i * 4 + 3] = xv2[i * 4 + 3] * rstd2 * wv.w;
  }
  #pragma unroll
  for (int j = 0; j < 8; ++j) mx = fmaxf(mx, fabsf(xn[j]));
  float bm = block_max(mx, red, 4);
  float xs = 127.f / fmaxf(bm, 1e-5f);
  float q[8];
  #pragma unroll
  for (int j = 0; j < 8; ++j) q[j] = fminf(fmaxf(rintf(xn[j] * xs), -128.f), 127.f);
  uint2 pw;
  pw.x = pk4i8(q[0], q[1], q[2], q[3]);
  pw.y = pk4i8(q[4], q[5], q[6], q[7]);
  *(uint2*)(xq + (size_t)r * HID_ + tid * 8) = pw;
  if (tid == 0) xs1[r] = xs;
}

// quantize h (silu*value) rows of 8192: bf16 in -> i8 out
__global__ __launch_bounds__(256) void quant_h_i8(const u16* __restrict__ hb, char* __restrict__ hq, float* __restrict__ xs2) {
  __shared__ float red[4];
  const int r = blockIdx.x, tid = threadIdx.x;
  const u16* hr = hb + (size_t)r * INTER_ + tid * 32;
  float f[32];
  #pragma unroll
  for (int k = 0; k < 4; ++k) {
    uint4 v = *(const uint4*)(hr + k * 8);
    bf8tof(v, &f[k * 8]);
  }
  float mx = 0.f;
  #pragma unroll
  for (int j = 0; j < 32; ++j) mx = fmaxf(mx, fabsf(f[j]));
  float bm = block_max(mx, red, 4);
  float xs = 127.f / fmaxf(bm, 1e-5f);
  u32 pw[8];
  #pragma unroll
  for (int k = 0; k < 8; ++k) {
    float q[4];
    #pragma unroll
    for (int j = 0; j < 4; ++j) q[j] = fminf(fmaxf(rintf(f[k * 4 + j] * xs), -128.f), 127.f);
    pw[k] = pk4i8(q[0], q[1], q[2], q[3]);
  }
  char* oq = hq + (size_t)r * INTER_ + tid * 32;
  *(uint4*)oq = uint4{pw[0], pw[1], pw[2], pw[3]};
  *(uint4*)(oq + 16) = uint4{pw[4], pw[5], pw[6], pw[7]};
  if (tid == 0) xs2[r] = xs;
}

// final: out = x2 + rs * rmsnorm(mlp, w)
__global__ __launch_bounds__(256) void final_resid(const float* __restrict__ x2, const u16* __restrict__ mlp,
    const float* __restrict__ wn, const float* __restrict__ rsp, float* __restrict__ out) {
  __shared__ float red[4];
  const int r = blockIdx.x, tid = threadIdx.x;
  const float rs = rsp[0];
  uint4 mv = *(const uint4*)(mlp + (size_t)r * HID_ + tid * 8);
  float f[8]; bf8tof(mv, f);
  float ss = 0.f;
  #pragma unroll
  for (int j = 0; j < 8; ++j) ss += f[j] * f[j];
  float tot = block_sum(ss, red, 4);
  float rstd = rsqrtf(tot * (1.f / HID_) + 1e-5f);
  const float* xr = x2 + (size_t)r * HID_;
  float* o = out + (size_t)r * HID_;
  #pragma unroll
  for (int i = 0; i < 2; ++i) {
    float4 xv = *(const float4*)(xr + tid * 8 + i * 4);
    float4 wv = *(const float4*)(wn + tid * 8 + i * 4);
    float4 ov;
    ov.x = xv.x + rs * f[i * 4 + 0] * rstd * wv.x;
    ov.y = xv.y + rs * f[i * 4 + 1] * rstd * wv.y;
    ov.z = xv.z + rs * f[i * 4 + 2] * rstd * wv.z;
    ov.w = xv.w + rs * f[i * 4 + 3] * rstd * wv.w;
    *(float4*)(o + tid * 8 + i * 4) = ov;
  }
}

// ---------- GEMM (bf16): C[M,*] = A[M,K] * B[N,K]^T ----------
// 2-phase double-buffered pipeline (T3-minimum): 128x128 tile, 512 thr / 8 waves (2Mx4N),
// BK=64, both-sides XOR swizzle, LDS 64KB (2 bufs) -> 2 blocks/CU.
// Prefetch of tile t+1 is issued BEFORE ds_read+MFMA of tile t; one barrier per K-step
// (implicit vmcnt(0)+lgkmcnt(0) drain) guarantees prefetch-landed AND reads-done.
template<int NBN>
__global__ __launch_bounds__(512, 4)
void gemm_bt2(const u16* __restrict__ A, const u16* __restrict__ Bw, u16* __restrict__ C,
              int K, int ldc) {
  __shared__ __align__(16) u16 As[2][128 * 64];
  __shared__ __align__(16) u16 Bs[2][128 * 64];
  const int tid = threadIdx.x;
  const int w = tid >> 6, lane = tid & 63;
  const int l15 = lane & 15, l4 = lane >> 4;
  const int wr = (w >> 2) * 64, wc = (w & 3) * 32;
  int id = blockIdx.x;
  const int cpx = (int)gridDim.x >> 3;
  id = (id & 7) * cpx + (id >> 3);
  const int bm = id / NBN, bn = id % NBN;
  const u16* Ag = A + (size_t)bm * 128 * K;
  const u16* Bg = Bw + (size_t)bn * 128 * K;
  // per-thread staging coords (2 chunks each for A and B)
  const int r0 = tid >> 3, s0 = (tid & 7) ^ (r0 & 7);
  const int r1 = (tid + 512) >> 3, s1 = ((tid + 512) & 7) ^ (r1 & 7);
  f32x4 acc[4][2] = {};
  // prologue: stage tile 0 into buf 0
  gload16(Ag + (size_t)r0 * K + s0 * 8, &As[0][tid * 8]);
  gload16(Ag + (size_t)r1 * K + s1 * 8, &As[0][(tid + 512) * 8]);
  gload16(Bg + (size_t)r0 * K + s0 * 8, &Bs[0][tid * 8]);
  gload16(Bg + (size_t)r1 * K + s1 * 8, &Bs[0][(tid + 512) * 8]);
  __syncthreads();
  int cur = 0;
  for (int kk = 0; kk < K; kk += 64) {
    const int nxt = kk + 64;
    if (nxt < K) {  // issue prefetch of next tile FIRST (overlaps ds_read+MFMA below)
      gload16(Ag + (size_t)r0 * K + nxt + s0 * 8, &As[cur ^ 1][tid * 8]);
      gload16(Ag + (size_t)r1 * K + nxt + s1 * 8, &As[cur ^ 1][(tid + 512) * 8]);
      gload16(Bg + (size_t)r0 * K + nxt + s0 * 8, &Bs[cur ^ 1][tid * 8]);
      gload16(Bg + (size_t)r1 * K + nxt + s1 * 8, &Bs[cur ^ 1][(tid + 512) * 8]);
    }
    bf16x8 af[4][2], bb[2][2];
    #pragma unroll
    for (int i = 0; i < 4; ++i) {
      const int ra = wr + i * 16 + l15;
      #pragma unroll
      for (int k2 = 0; k2 < 2; ++k2) {
        const int g8 = k2 * 4 + l4;
        af[i][k2] = ldfrag(&As[cur][ra * 64 + ((g8 ^ (ra & 7)) * 8)]);
      }
    }
    #pragma unroll
    for (int j = 0; j < 2; ++j) {
      const int rb = wc + j * 16 + l15;
      #pragma unroll
      for (int k2 = 0; k2 < 2; ++k2) {
        const int g8 = k2 * 4 + l4;
        bb[j][k2] = ldfrag(&Bs[cur][rb * 64 + ((g8 ^ (rb & 7)) * 8)]);
      }
    }
    #pragma unroll
    for (int i = 0; i < 4; ++i)
      #pragma unroll
      for (int j = 0; j < 2; ++j)
        #pragma unroll
        for (int k2 = 0; k2 < 2; ++k2)
          acc[i][j] = __builtin_amdgcn_mfma_f32_16x16x32_bf16(af[i][k2], bb[j][k2], acc[i][j], 0, 0, 0);
    __syncthreads();   // drains prefetch (vmcnt 0) + all waves done reading buf[cur]
    cur ^= 1;
  }
  #pragma unroll
  for (int i = 0; i < 4; ++i) {
    #pragma unroll
    for (int r = 0; r < 4; ++r) {
      const int row = bm * 128 + wr + i * 16 + l4 * 4 + r;
      #pragma unroll
      for (int j = 0; j < 2; ++j) {
        const int col = bn * 128 + wc + j * 16 + l15;
        C[(size_t)row * ldc + col] = f2bf(acc[i][j][r]);
      }
    }
  }
}

// ---------- FFN GEMMs: i8 MFMA, BK=128, both-sides XOR swizzle ----------
__global__ __launch_bounds__(512, 2)
void gemm_up_i8(const char* __restrict__ A, const char* __restrict__ Bw, u16* __restrict__ H,
                const float* __restrict__ wsp, const float* __restrict__ xs) {
  const int K = HID_;
  __shared__ __align__(16) char As[128 * 128];
  __shared__ __align__(16) char Gs[128 * 128];
  __shared__ __align__(16) char Vs[128 * 128];
  const int tid = threadIdx.x;
  const int w = tid >> 6, lane = tid & 63;
  const int l15 = lane & 15, l4 = lane >> 4;
  const int wr = (w >> 2) * 64, wc = (w & 3) * 32;
  int id = blockIdx.x;
  const int cpx = (int)gridDim.x >> 3;
  id = (id & 7) * cpx + (id >> 3);
  const int bm = id & 31, bn = id >> 5;
  const char* Ag = A + (size_t)bm * 128 * K;
  const char* Gg = Bw + (size_t)bn * 128 * K;
  const char* Vg = Bw + ((size_t)INTER_ + bn * 128) * K;
  i32x4 ag[4][2] = {}, av[4][2] = {};
  for (int kk = 0; kk < K; kk += 128) {
    #pragma unroll
    for (int p = 0; p < 2; ++p) {
      const int idx = tid + p * 512;
      const int row = idx >> 3, slot = idx & 7;
      const int ss = slot ^ (row & 7);
      gload16(Ag + (size_t)row * K + kk + ss * 16, &As[idx * 16]);
      gload16(Gg + (size_t)row * K + kk + ss * 16, &Gs[idx * 16]);
      gload16(Vg + (size_t)row * K + kk + ss * 16, &Vs[idx * 16]);
    }
    __syncthreads();
    i32x4 af_[4][2], gf_[2][2], vf_[2][2];
    #pragma unroll
    for (int i = 0; i < 4; ++i) {
      const int r = wr + i * 16 + l15;
      #pragma unroll
      for (int k2 = 0; k2 < 2; ++k2) {
        const int j = k2 * 4 + l4;
        af_[i][k2] = *(const i32x4*)&As[r * 128 + ((j ^ (r & 7)) * 16)];
      }
    }
    #pragma unroll
    for (int jj = 0; jj < 2; ++jj) {
      const int r = wc + jj * 16 + l15;
      #pragma unroll
      for (int k2 = 0; k2 < 2; ++k2) {
        const int j = k2 * 4 + l4;
        gf_[jj][k2] = *(const i32x4*)&Gs[r * 128 + ((j ^ (r & 7)) * 16)];
        vf_[jj][k2] = *(const i32x4*)&Vs[r * 128 + ((j ^ (r & 7)) * 16)];
      }
    }
    #pragma unroll
    for (int i = 0; i < 4; ++i)
      #pragma unroll
      for (int jj = 0; jj < 2; ++jj)
        #pragma unroll
        for (int k2 = 0; k2 < 2; ++k2) {
          ag[i][jj] = __builtin_amdgcn_mfma_i32_16x16x64_i8(af_[i][k2], gf_[jj][k2], ag[i][jj], 0, 0, 0);
          av[i][jj] = __builtin_amdgcn_mfma_i32_16x16x64_i8(af_[i][k2], vf_[jj][k2], av[i][jj], 0, 0, 0);
        }
    __syncthreads();
  }
  const float ws0 = wsp[0];
  #pragma unroll
  for (int i = 0; i < 4; ++i) {
    #pragma unroll
    for (int r = 0; r < 4; ++r) {
      const int row = bm * 128 + wr + i * 16 + l4 * 4 + r;
      const float scl = ws0 / xs[row];
      #pragma unroll
      for (int jj = 0; jj < 2; ++jj) {
        const int col = bn * 128 + wc + jj * 16 + l15;
        const float og = (float)ag[i][jj][r] * scl;
        const float ov = (float)av[i][jj][r] * scl;
        const float hv = og * ov / (1.f + expf(-og));  // silu(og)*ov
        H[(size_t)row * INTER_ + col] = f2bf(hv);
      }
    }
  }
}

// down-proj (round-8 proven config): 256 thr, 128x128 tile, grid dim3(16,32) bn-fastest
__global__ __launch_bounds__(256, 2)
void gemm_dn_i8(const char* __restrict__ A, const char* __restrict__ Bw, u16* __restrict__ C,
                const float* __restrict__ wsp, const float* __restrict__ xs) {
  const int N = HID_, K = INTER_;
  __shared__ __align__(16) char As[128 * 128];
  __shared__ __align__(16) char Bs[128 * 128];
  const int tid = threadIdx.x;
  const int wv = tid >> 6, lane = tid & 63;
  const int l15 = lane & 15, l4 = lane >> 4;
  const int wr = (wv >> 1) * 64, wc = (wv & 1) * 64;
  const int bm = blockIdx.y, bn = blockIdx.x;
  const char* Ag = A + (size_t)bm * 128 * K;
  const char* Bg = Bw + (size_t)bn * 128 * K;
  i32x4 acc[4][4] = {};
  for (int kk = 0; kk < K; kk += 128) {
    #pragma unroll
    for (int p = 0; p < 4; ++p) {
      const int idx = tid + p * 256;
      const int row = idx >> 3, slot = idx & 7;
      const int ss = slot ^ (row & 7);
      gload16(Ag + (size_t)row * K + kk + ss * 16, &As[idx * 16]);
      gload16(Bg + (size_t)row * K + kk + ss * 16, &Bs[idx * 16]);
    }
    __syncthreads();
    i32x4 af_[4][2], bb_[4][2];
    #pragma unroll
    for (int i = 0; i < 4; ++i) {
      const int ra = wr + i * 16 + l15;
      const int rb = wc + i * 16 + l15;
      #pragma unroll
      for (int k2 = 0; k2 < 2; ++k2) {
        const int j = k2 * 4 + l4;
        af_[i][k2] = *(const i32x4*)&As[ra * 128 + ((j ^ (ra & 7)) * 16)];
        bb_[i][k2] = *(const i32x4*)&Bs[rb * 128 + ((j ^ (rb & 7)) * 16)];
      }
    }
    #pragma unroll
    for (int i = 0; i < 4; ++i)
      #pragma unroll
      for (int j = 0; j < 4; ++j)
        #pragma unroll
        for (int k2 = 0; k2 < 2; ++k2)
          acc[i][j] = __builtin_amdgcn_mfma_i32_16x16x64_i8(af_[i][k2], bb_[j][k2], acc[i][j], 0, 0, 0);
    __syncthreads();
  }
  const float ws0 = wsp[0];
  #pragma unroll
  for (int i = 0; i < 4; ++i) {
    #pragma unroll
    for (int r = 0; r < 4; ++r) {
      const int row = bm * 128 + wr + i * 16 + l4 * 4 + r;
      const float scl = ws0 / xs[row];
      #pragma unroll
      for (int j = 0; j < 4; ++j) {
        const int col = bn * 128 + wc + j * 16 + l15;
        C[(size_t)row * N + col] = f2bf((float)acc[i][j][r] * scl);
      }
    }
  }
}

// ---------- attention (MFMA); q/k/v are column slices of fused qkv (row stride ldq) ----------
DEV void write_otile(const f32x16 oc, float invl, char* stgB, u16* alocrow,
                     int da, int l31, int hi, int lane) {
  #pragma unroll
  for (int r = 0; r < 16; ++r) {
    const int dl = (r & 3) + 8 * (r >> 2) + 4 * hi;
    *(u16*)(stgB + l31 * 64 + ((dl * 2) ^ ((l31 & 3) << 4))) = f2bf(oc[r] * invl);
  }
  #pragma unroll
  for (int p = 0; p < 2; ++p) {
    const int s = lane >> 1;
    const int d8 = (lane & 1) * 8 + p * 16;
    const uint4 val = *(const uint4*)(stgB + s * 64 + ((d8 * 2) ^ ((s & 3) << 4)));
    *(uint4*)(alocrow + (size_t)s * HD_ + da * 32 + d8) = val;
  }
}

__global__ __launch_bounds__(512)
void attn_local_mfma(const u16* __restrict__ q, const u16* __restrict__ k, const u16* __restrict__ v,
                     u16* __restrict__ aloc, float* __restrict__ Useg, float* __restrict__ yseg, int ldq) {
  __shared__ __align__(16) u16 Ks[512 * 64];
  __shared__ __align__(16) u16 VT[64 * 512];
  __shared__ __align__(16) u16 SP[9216];
  const int bid = blockIdx.x;
  const int c = bid >> 7, bh = bid & 127;
  const int b = bh >> 5, h = bh & 31;
  const int tid = threadIdx.x, w = tid >> 6, lane = tid & 63;
  const int l31 = lane & 31, hi = lane >> 5;
  const size_t rowbase = ((size_t)b * S_ + c * SEG_) * (size_t)ldq + h * HD_;
  const u16* qg = q + rowbase;
  const u16* kg = k + rowbase;
  const u16* vg = v + rowbase;
  char* KsB = (char*)Ks;
  char* VTB = (char*)VT;
  #pragma unroll
  for (int p = 0; p < 8; ++p) {
    const int idx = tid + p * 512;
    const int t = idx >> 3, dg = idx & 7;
    const uint4 kv = *(const uint4*)(kg + (size_t)t * ldq + dg * 8);
    *(uint4*)(KsB + t * 128 + ((dg * 16) ^ ((t & 7) << 4))) = kv;
  }
  {
    const int t = w * 64 + lane;
    #pragma unroll
    for (int dg = 0; dg < 8; ++dg) {
      const uint4 vv = *(const uint4*)(vg + (size_t)t * ldq + dg * 8);
      const u16* e = (const u16*)&vv;
      #pragma unroll
      for (int j = 0; j < 8; ++j) {
        const int d = dg * 8 + j;
        *(u16*)(VTB + d * 1024 + ((t * 2) ^ ((d & 7) << 4))) = e[j];
      }
    }
  }
  // balanced wave->q-tile map: wave w owns tiles {w, 15-w} (17 t-block iters each)
  uint4 qf[2][4];
  #pragma unroll
  for (int qi = 0; qi < 2; ++qi) {
    const int qt = qi == 0 ? w : 15 - w;
    #pragma unroll
    for (int ks = 0; ks < 4; ++ks)
      qf[qi][ks] = *(const uint4*)(qg + (size_t)(qt * 32 + l31) * ldq + ks * 16 + hi * 8);
  }
  __syncthreads();

  const size_t arow = (size_t)(b * NH_ + h) * S_ + c * SEG_;
  const int swzk = (l31 & 7) << 4;
  char* stgB = (char*)SP + w * 2048;
  #pragma unroll
  for (int qi = 0; qi < 2; ++qi) {
    const int qt = qi == 0 ? w : 15 - w;
    f32x16 o0 = {}, o1 = {};
    float m = -3e38f, l = 0.f;
    const int nb = qt + 1;
    for (int tb = 0; tb < nb; ++tb) {
      f32x16 st = {};
      #pragma unroll
      for (int ks = 0; ks < 4; ++ks) {
        const uint4 ka = *(const uint4*)(KsB + (tb * 32 + l31) * 128 + (((ks * 16 + hi * 8) * 2) ^ swzk));
        st = __builtin_amdgcn_mfma_f32_32x32x16_bf16(__builtin_bit_cast(bf16x8, ka),
                                                     __builtin_bit_cast(bf16x8, qf[qi][ks]), st, 0, 0, 0);
      }
      if (tb == nb - 1) {
        #pragma unroll
        for (int r = 0; r < 16; ++r) {
          const int tl = (r & 3) + 8 * (r >> 2) + 4 * hi;
          if (tl > l31) st[r] = -3e38f;
        }
      }
      float tm = st[0];
      #pragma unroll
      for (int r = 1; r < 16; ++r) tm = fmaxf(tm, st[r]);
      tm = fmaxf(tm, __shfl_xor(tm, 32, 64));
      const float mn = fmaxf(m, tm);
      const float fac = __expf((m - mn) * 0.125f);
      float pr[16]; float ps = 0.f;
      #pragma unroll
      for (int r = 0; r < 16; ++r) { pr[r] = __expf((st[r] - mn) * 0.125f); ps += pr[r]; }
      ps += __shfl_xor(ps, 32, 64);
      l = l * fac + ps;
      m = mn;
      #pragma unroll
      for (int r = 0; r < 16; ++r) { o0[r] *= fac; o1[r] *= fac; }
      #pragma unroll
      for (int c2 = 0; c2 < 2; ++c2) {
        const int bi = c2 * 8;
        const u32 a0 = pkbf(pr[bi + 0], pr[bi + 1]);
        const u32 a1 = pkbf(pr[bi + 2], pr[bi + 3]);
        const u32 a2 = pkbf(pr[bi + 4], pr[bi + 5]);
        const u32 a3 = pkbf(pr[bi + 6], pr[bi + 7]);
        const u32 x0 = (u32)__shfl_xor((int)a0, 32, 64);
        const u32 x1 = (u32)__shfl_xor((int)a1, 32, 64);
        const u32 x2 = (u32)__shfl_xor((int)a2, 32, 64);
        const u32 x3 = (u32)__shfl_xor((int)a3, 32, 64);
        uint4 pw;
        pw.x = hi ? x2 : a0;
        pw.y = hi ? x3 : a1;
        pw.z = hi ? a2 : x0;
        pw.w = hi ? a3 : x1;
        const bf16x8 pfr = __builtin_bit_cast(bf16x8, pw);
        const int tO = (tb * 32 + c2 * 16 + hi * 8) * 2;
        const uint4 v0 = *(const uint4*)(VTB + l31 * 1024 + (tO ^ swzk));
        const uint4 v1 = *(const uint4*)(VTB + (32 + l31) * 1024 + (tO ^ swzk));
        o0 = __builtin_amdgcn_mfma_f32_32x32x16_bf16(__builtin_bit_cast(bf16x8, v0), pfr, o0, 0, 0, 0);
        o1 = __builtin_amdgcn_mfma_f32_32x32x16_bf16(__builtin_bit_cast(bf16x8, v1), pfr, o1, 0, 0, 0);
      }
    }
    const float invl = 1.f / l;
    u16* alocrow = aloc + (arow + qt * 32) * HD_;
    write_otile(o0, invl, stgB, alocrow, 0, l31, hi, lane);
    write_otile(o1, invl, stgB, alocrow, 1, l31, hi, lane);
  }

  __syncthreads();
  float* Ured = (float*)SP;
  float* yred = (float*)((char*)SP + 16384);
  for (int i = tid; i < 4096; i += 512) Ured[i] = 0.f;
  yred[tid] = 0.f;
  __syncthreads();
  f32x16 u00 = {}, u01 = {}, u10 = {}, u11 = {};
  float y0 = 0.f, y1 = 0.f;
  #pragma unroll
  for (int kc = 0; kc < 4; ++kc) {
    const int t0 = w * 64 + kc * 16 + hi * 8;
    uint4 af[2];
    #pragma unroll
    for (int da2 = 0; da2 < 2; ++da2) {
      const int d = da2 * 32 + l31;
      u32 wds[4];
      #pragma unroll
      for (int jp = 0; jp < 4; ++jp) {
        const int ta = t0 + jp * 2;
        const int tb2 = ta + 1;
        const float kfa = bf2f(*(const u16*)(KsB + ta * 128 + ((d * 2) ^ ((ta & 7) << 4))));
        const float kfb = bf2f(*(const u16*)(KsB + tb2 * 128 + ((d * 2) ^ ((tb2 & 7) << 4))));
        const float sa = kfa > 0.f ? kfa + 1.f : __expf(kfa);
        const float sb = kfb > 0.f ? kfb + 1.f : __expf(kfb);
        if (da2 == 0) y0 += sa + sb; else y1 += sa + sb;
        wds[jp] = pkbf(sa, sb);
      }
      af[da2].x = wds[0]; af[da2].y = wds[1]; af[da2].z = wds[2]; af[da2].w = wds[3];
    }
    const int tO = t0 * 2;
    const uint4 vb0 = *(const uint4*)(VTB + l31 * 1024 + (tO ^ swzk));
    const uint4 vb1 = *(const uint4*)(VTB + (32 + l31) * 1024 + (tO ^ swzk));
    const bf16x8 a0f = __builtin_bit_cast(bf16x8, af[0]);
    const bf16x8 a1f = __builtin_bit_cast(bf16x8, af[1]);
    const bf16x8 b0f = __builtin_bit_cast(bf16x8, vb0);
    const bf16x8 b1f = __builtin_bit_cast(bf16x8, vb1);
    u00 = __builtin_amdgcn_mfma_f32_32x32x16_bf16(a0f, b0f, u00, 0, 0, 0);
    u01 = __builtin_amdgcn_mfma_f32_32x32x16_bf16(a0f, b1f, u01, 0, 0, 0);
    u10 = __builtin_amdgcn_mfma_f32_32x32x16_bf16(a1f, b0f, u10, 0, 0, 0);
    u11 = __builtin_amdgcn_mfma_f32_32x32x16_bf16(a1f, b1f, u11, 0, 0, 0);
  }
  y0 += __shfl_xor(y0, 32, 64);
  y1 += __shfl_xor(y1, 32, 64);
  if (hi == 0) { yred[w * 64 + l31] = y0; yred[w * 64 + 32 + l31] = y1; }
  for (int ww = 0; ww < 8; ++ww) {
    if (w == ww) {
      #pragma unroll
      for (int r = 0; r < 16; ++r) {
        const int dl = (r & 3) + 8 * (r >> 2) + 4 * hi;
        Ured[dl * 64 + l31]            += u00[r];
        Ured[dl * 64 + 32 + l31]       += u01[r];
        Ured[(32 + dl) * 64 + l31]     += u10[r];
        Ured[(32 + dl) * 64 + 32 + l31]+= u11[r];
      }
    }
    __syncthreads();
  }
  float* Ug = Useg + (size_t)(c * 128 + bh) * 4096;
  for (int i = tid; i < 4096; i += 512) Ug[i] = Ured[i];
  if (tid < 64) {
    float a2 = 0.f;
    #pragma unroll
    for (int ww = 0; ww < 8; ++ww) a2 += yred[ww * 64 + tid];
    yseg[(size_t)(c * 128 + bh) * 64 + tid] = a2;
  }
}

__global__ __launch_bounds__(256)
void attn_prefix(const float* __restrict__ Useg, const float* __restrict__ yseg,
                 float* __restrict__ Mpre, float* __restrict__ zpre) {
  const int bh = blockIdx.x, tid = threadIdx.x;
  for (int idx = tid; idx < 4096; idx += 256) {
    float a2 = 0.f;
    #pragma unroll
    for (int c = 0; c < 8; ++c) {
      const size_t o = ((size_t)(c * 128 + bh)) * 4096 + idx;
      Mpre[o] = a2;
      a2 += Useg[o];
    }
  }
  if (tid < 64) {
    float a2 = 0.f;
    #pragma unroll
    for (int c = 0; c < 8; ++c) {
      const size_t o = ((size_t)(c * 128 + bh)) * 64 + tid;
      zpre[o] = a2;
      a2 += yseg[o];
    }
  }
}

__global__ __launch_bounds__(512)
void attn_combine(const u16* __restrict__ q, const u16* __restrict__ aloc,
                  const float* __restrict__ Mpre, const float* __restrict__ zpre,
                  const float* __restrict__ beta, u16* __restrict__ attno, int ldq) {
  __shared__ __align__(16) u16 MbT[64 * 64];
  __shared__ float z_lds[64];
  __shared__ float amem[8][16 * 65];
  const int bid = blockIdx.x;
  const int c = bid >> 7, bh = bid & 127;
  const int b = bh >> 5, h = bh & 31;
  const int tid = threadIdx.x, w = tid >> 6, lane = tid & 63;
  const int l15 = lane & 15, l4 = lane >> 4;
  const size_t pre = (size_t)(c * 128 + bh);
  char* MbB = (char*)MbT;
  for (int i = tid; i < 4096; i += 512) {
    const int d = i >> 6, e = i & 63;
    *(u16*)(MbB + (((e * 64 + d) * 2) ^ ((e & 7) << 4))) = f2bf(Mpre[pre * 4096 + i]);
  }
  if (tid < 64) z_lds[tid] = zpre[pre * 64 + tid];
  __syncthreads();
  bf16x8 bb[2][4];
  #pragma unroll
  for (int ks = 0; ks < 2; ++ks)
    #pragma unroll
    for (int jt = 0; jt < 4; ++jt) {
      const int e = jt * 16 + l15;
      const uint4 u = *(const uint4*)(MbB + (((e * 64 + ks * 32 + l4 * 8) * 2) ^ ((e & 7) << 4)));
      bb[ks][jt] = __builtin_bit_cast(bf16x8, u);
    }
  const float g = sigmoidf_(beta[h]);
  const float og = 1.f - g;
  const u16* qg = q + ((size_t)b * S_ + c * SEG_) * ldq + h * HD_;
  const size_t arow = (size_t)(b * NH_ + h) * S_ + c * SEG_;
  u16* orow = attno + ((size_t)b * S_ + c * SEG_) * HID_ + h * HD_;
  const int rr = lane >> 2, cq = (lane & 3) * 16;
  #pragma unroll
  for (int mi = 0; mi < 4; ++mi) {
    const int s0 = w * 64 + mi * 16;
    f32x4 acc[4] = {};
    float pd = 0.f;
    #pragma unroll
    for (int ks = 0; ks < 2; ++ks) {
      const uint4 qv = *(const uint4*)(qg + (size_t)(s0 + l15) * ldq + ks * 32 + l4 * 8);
      float f[8]; bf8tof(qv, f);
      float sq[8];
      #pragma unroll
      for (int j = 0; j < 8; ++j) {
        sq[j] = f[j] > 0.f ? f[j] + 1.f : __expf(f[j]);
        pd = fmaf(sq[j], z_lds[ks * 32 + l4 * 8 + j], pd);
      }
      uint4 pw;
      pw.x = pkbf(sq[0], sq[1]); pw.y = pkbf(sq[2], sq[3]);
      pw.z = pkbf(sq[4], sq[5]); pw.w = pkbf(sq[6], sq[7]);
      const bf16x8 af = __builtin_bit_cast(bf16x8, pw);
      #pragma unroll
      for (int jt = 0; jt < 4; ++jt)
        acc[jt] = __builtin_amdgcn_mfma_f32_16x16x32_bf16(af, bb[ks][jt], acc[jt], 0, 0, 0);
    }
    pd += __shfl_xor(pd, 16, 64);
    pd += __shfl_xor(pd, 32, 64);
    pd += 1e-6f;
    float dinv[4];
    #pragma unroll
    for (int r = 0; r < 4; ++r) dinv[r] = 1.f / __shfl(pd, l4 * 4 + r, 64);
    #pragma unroll
    for (int jt = 0; jt < 4; ++jt)
      #pragma unroll
      for (int r = 0; r < 4; ++r)
        amem[w][(l4 * 4 + r) * 65 + jt * 16 + l15] = acc[jt][r] * dinv[r];
    const int s = s0 + rr;
    const u16* alr = aloc + (arow + s) * HD_ + cq;
    const uint4 a0 = *(const uint4*)alr;
    const uint4 a1 = *(const uint4*)(alr + 8);
    float alf[16];
    bf8tof(a0, alf); bf8tof(a1, alf + 8);
    float ov[16];
    #pragma unroll
    for (int t = 0; t < 16; ++t)
      ov[t] = g * amem[w][rr * 65 + cq + t] + og * alf[t];
    *(uint4*)(orow + (size_t)s * HID_ + cq) = f8tobf(ov);
    *(uint4*)(orow + (size_t)s * HID_ + cq + 8) = f8tobf(ov + 8);
  }
}

// ---------- launch ----------
extern "C" void kernel_launch(void* const* d_in, const int* in_sizes, int n_in,
                              void* d_out, int out_size, void* d_ws, size_t ws_size,
                              hipStream_t stream) {
  const float* x    = (const float*)d_in[0];
  const float* wq   = (const float*)d_in[1];
  const float* wk   = (const float*)d_in[2];
  const float* wv   = (const float*)d_in[3];
  const float* wo   = (const float*)d_in[4];
  const float* beta = (const float*)d_in[5];
  const float* gate = (const float*)d_in[6];
  const float* anw  = (const float*)d_in[7];
  const float* mnw  = (const float*)d_in[8];
  const float* arnw = (const float*)d_in[9];
  const float* arsc = (const float*)d_in[10];
  const float* mrnw = (const float*)d_in[11];
  const float* mrsc = (const float*)d_in[12];
  const float* fup  = (const float*)d_in[13];
  const float* fdn  = (const float*)d_in[14];

  char* W = (char*)d_ws;
  const size_t MB = 1ull << 20;
  u16*   xn1   = (u16*)(W + 0);
  u16*   attno = (u16*)(W + 0);
  u16*   mlpb  = (u16*)(W + 0);
  u16*   qkv   = (u16*)(W + 64 * MB);
  char*  xq1   = (char*)(W + 64 * MB);
  u16*   aob   = (u16*)(W + 128 * MB);
  u16*   hbuf  = (u16*)(W + 128 * MB);
  u16*   alocb = (u16*)(W + 256 * MB);
  float* x2    = (float*)(W + 192 * MB);
  float* Useg  = (float*)(W + 320 * MB);
  float* Mpre  = (float*)(W + 336 * MB);
  float* yseg  = (float*)(W + 352 * MB);
  float* zpre  = (float*)(W + 352 * MB + 262144);
  float* xs1   = (float*)(W + 352 * MB + 524288);
  float* xs2   = (float*)(W + 352 * MB + 589824);
  float* wsu   = (float*)(W + 352 * MB + 655360);
  float* wsd   = (float*)(W + 352 * MB + 655616);
  float* partU = (float*)(W + 352 * MB + 655872);
  float* partD = (float*)(W + 352 * MB + 664064);
  u16*   w16qkv= (u16*)(W + 353 * MB);          // [6144,2048] = wq|wk|wv
  u16*   w16o  = (u16*)(W + 377 * MB);
  char*  wqup  = (char*)(W + 385 * MB);
  char*  wqdn  = (char*)(W + 417 * MB);
  char*  hq    = (char*)(W + 433 * MB);

  // weight prep
  castf2b<<<4096, 256, 0, stream>>>(wq, w16qkv);
  castf2b<<<4096, 256, 0, stream>>>(wk, w16qkv + (size_t)HID_ * HID_);
  castf2b<<<4096, 256, 0, stream>>>(wv, w16qkv + 2 * (size_t)HID_ * HID_);
  castf2b<<<4096, 256, 0, stream>>>(wo, w16o);
  absmean_part<<<2048, 256, 0, stream>>>(fup, partU);
  absmean_part<<<1024, 256, 0, stream>>>(fdn, partD);
  absmean_fin<<<1, 256, 0, stream>>>(partU, 2048, 1.f / 33554432.f, wsu);
  absmean_fin<<<1, 256, 0, stream>>>(partD, 1024, 1.f / 16777216.f, wsd);
  ternarize_i8<<<32768, 256, 0, stream>>>(fup, wsu, wqup);
  ternarize_i8<<<16384, 256, 0, stream>>>(fdn, wsd, wqdn);

  // attention path: fused QKV GEMM -> qkv[16384,6144]
  rmsnorm_cast<<<16384, 256, 0, stream>>>(x, anw, xn1);
  gemm_bt2<48><<<6144, 512, 0, stream>>>(xn1, w16qkv, qkv, HID_, LDQ_);
  attn_local_mfma<<<1024, 512, 0, stream>>>(qkv, qkv + HID_, qkv + 2 * HID_, alocb, Useg, yseg, LDQ_);
  attn_prefix<<<128, 256, 0, stream>>>(Useg, yseg, Mpre, zpre);
  attn_combine<<<1024, 512, 0, stream>>>(qkv, alocb, Mpre, zpre, beta, attno, LDQ_);
  gemm_bt2<16><<<2048, 512, 0, stream>>>(attno, w16o, aob, HID_, HID_);
  resid1_rms2<<<16384, 256, 0, stream>>>(x, aob, gate, arnw, arsc, mnw, x2, xq1, xs1);

  // MLP path (4 token-chunks of 4096 rows, i8 MFMA)
  for (int cc = 0; cc < 4; ++cc) {
    const size_t base = (size_t)cc * CHROWS_;
    gemm_up_i8<<<2048, 512, 0, stream>>>(xq1 + base * HID_, wqup, hbuf, wsu, xs1 + base);
    quant_h_i8<<<4096, 256, 0, stream>>>(hbuf, hq, xs2 + base);
    gemm_dn_i8<<<dim3(16, 32), 256, 0, stream>>>(hq, wqdn, mlpb + base * HID_, wsd, xs2 + base);
  }
  final_resid<<<16384, 256, 0, stream>>>(x2, mlpb, mrnw, mrsc, (float*)d_out);
}

// Round 12
// 1974.152 us; speedup vs baseline: 1.0524x; 1.0524x over previous
//
#include <hip/hip_runtime.h>
#include <cstdint>
#include <cstddef>

typedef unsigned int u32;
typedef unsigned short u16;
typedef __bf16 bf16x8 __attribute__((ext_vector_type(8)));
typedef float f32x4 __attribute__((ext_vector_type(4)));
typedef float f32x16 __attribute__((ext_vector_type(16)));
typedef int i32x4 __attribute__((ext_vector_type(4)));

#define DEV static __device__ __forceinline__

// ---------- helpers ----------
DEV float bf2f(u16 u) { u32 x = ((u32)u) << 16; return __builtin_bit_cast(float, x); }
DEV u16 f2bf(float f) {
  u32 u = __builtin_bit_cast(u32, f);
  u32 r = (u + 0x7fffu + ((u >> 16) & 1u)) >> 16;  // RNE
  return (u16)r;
}
DEV u32 pkbf(float a, float b) {
  __bf16 ba = (__bf16)a, bb = (__bf16)b;
  return (u32)__builtin_bit_cast(u16, ba) | ((u32)__builtin_bit_cast(u16, bb) << 16);
}
DEV u32 pk4i8(float a, float b, float c, float d) {
  return (u32)(unsigned char)(char)a | ((u32)(unsigned char)(char)b << 8) |
         ((u32)(unsigned char)(char)c << 16) | ((u32)(unsigned char)(char)d << 24);
}
DEV void bf8tof(const uint4 v, float* f) {
  f[0] = bf2f((u16)(v.x & 0xffffu)); f[1] = bf2f((u16)(v.x >> 16));
  f[2] = bf2f((u16)(v.y & 0xffffu)); f[3] = bf2f((u16)(v.y >> 16));
  f[4] = bf2f((u16)(v.z & 0xffffu)); f[5] = bf2f((u16)(v.z >> 16));
  f[6] = bf2f((u16)(v.w & 0xffffu)); f[7] = bf2f((u16)(v.w >> 16));
}
DEV uint4 f8tobf(const float* f) {
  uint4 r;
  r.x = (u32)f2bf(f[0]) | ((u32)f2bf(f[1]) << 16);
  r.y = (u32)f2bf(f[2]) | ((u32)f2bf(f[3]) << 16);
  r.z = (u32)f2bf(f[4]) | ((u32)f2bf(f[5]) << 16);
  r.w = (u32)f2bf(f[6]) | ((u32)f2bf(f[7]) << 16);
  return r;
}
DEV float sigmoidf_(float x) { return 1.f / (1.f + expf(-x)); }

DEV float wred_sum(float v) {
  #pragma unroll
  for (int m = 32; m; m >>= 1) v += __shfl_xor(v, m, 64);
  return v;
}
DEV float wred_max(float v) {
  #pragma unroll
  for (int m = 32; m; m >>= 1) v = fmaxf(v, __shfl_xor(v, m, 64));
  return v;
}
DEV float block_sum(float v, float* red, int nw) {
  v = wred_sum(v);
  int w = threadIdx.x >> 6, l = threadIdx.x & 63;
  if (l == 0) red[w] = v;
  __syncthreads();
  float t = red[0];
  for (int i = 1; i < nw; ++i) t += red[i];
  __syncthreads();
  return t;
}
DEV float block_max(float v, float* red, int nw) {
  v = wred_max(v);
  int w = threadIdx.x >> 6, l = threadIdx.x & 63;
  if (l == 0) red[w] = v;
  __syncthreads();
  float t = red[0];
  for (int i = 1; i < nw; ++i) t = fmaxf(t, red[i]);
  __syncthreads();
  return t;
}
DEV void gload16(const void* g, void* l) {
  __builtin_amdgcn_global_load_lds((const __attribute__((address_space(1))) void*)g,
                                   (__attribute__((address_space(3))) void*)l, 16, 0, 0);
}
DEV bf16x8 ldfrag(const u16* p) {
  uint4 u = *(const uint4*)p;
  return __builtin_bit_cast(bf16x8, u);
}

// ---------- constants ----------
#define BN_ 4
#define S_ 4096
#define HID_ 2048
#define NH_ 32
#define HD_ 64
#define INTER_ 8192
#define NBSEG_ 8
#define SEG_ 512
#define TOK_ 16384
#define CHROWS_ 4096   // MLP token-chunk rows
#define LDQ_ 6144      // fused qkv row stride

// ---------- elementwise / prep kernels ----------
__global__ __launch_bounds__(256) void castf2b(const float* __restrict__ a, u16* __restrict__ o) {
  size_t idx = ((size_t)blockIdx.x * 256 + threadIdx.x) * 4;
  float4 v = *(const float4*)(a + idx);
  float f[4] = {v.x, v.y, v.z, v.w};
  uint2 r;
  r.x = (u32)f2bf(f[0]) | ((u32)f2bf(f[1]) << 16);
  r.y = (u32)f2bf(f[2]) | ((u32)f2bf(f[3]) << 16);
  *(uint2*)(o + idx) = r;
}

__global__ __launch_bounds__(256) void absmean_part(const float* __restrict__ w, float* __restrict__ part) {
  __shared__ float red[4];
  size_t base = (size_t)blockIdx.x * 16384 + threadIdx.x * 4;
  float s = 0.f;
  #pragma unroll
  for (int i = 0; i < 16; ++i) {
    float4 v = *(const float4*)(w + base + (size_t)i * 1024);
    s += fabsf(v.x) + fabsf(v.y) + fabsf(v.z) + fabsf(v.w);
  }
  float t = block_sum(s, red, 4);
  if (threadIdx.x == 0) part[blockIdx.x] = t;
}

__global__ __launch_bounds__(256) void absmean_fin(const float* __restrict__ part, int n, float invN, float* __restrict__ outp) {
  __shared__ float red[4];
  float s = 0.f;
  for (int i = threadIdx.x; i < n; i += 256) s += part[i];
  float t = block_sum(s, red, 4);
  if (threadIdx.x == 0) outp[0] = t * invN + 1e-8f;
}

// ternary weights -> i8
__global__ __launch_bounds__(256) void ternarize_i8(const float* __restrict__ w, const float* __restrict__ wsp, char* __restrict__ o) {
  size_t idx = ((size_t)blockIdx.x * 256 + threadIdx.x) * 4;
  const float inv = 1.f / wsp[0];
  float4 v = *(const float4*)(w + idx);
  float q0 = rintf(fminf(fmaxf(v.x * inv, -1.f), 1.f));
  float q1 = rintf(fminf(fmaxf(v.y * inv, -1.f), 1.f));
  float q2 = rintf(fminf(fmaxf(v.z * inv, -1.f), 1.f));
  float q3 = rintf(fminf(fmaxf(v.w * inv, -1.f), 1.f));
  *(u32*)(o + idx) = pk4i8(q0, q1, q2, q3);
}

__global__ __launch_bounds__(256) void rmsnorm_cast(const float* __restrict__ x, const float* __restrict__ wn, u16* __restrict__ o) {
  __shared__ float red[4];
  const int r = blockIdx.x, tid = threadIdx.x;
  const float* xr = x + (size_t)r * HID_;
  float vx[8];
  #pragma unroll
  for (int i = 0; i < 2; ++i) {
    float4 t = *(const float4*)(xr + tid * 8 + i * 4);
    vx[i * 4 + 0] = t.x; vx[i * 4 + 1] = t.y; vx[i * 4 + 2] = t.z; vx[i * 4 + 3] = t.w;
  }
  float ss = 0.f;
  #pragma unroll
  for (int j = 0; j < 8; ++j) ss += vx[j] * vx[j];
  float tot = block_sum(ss, red, 4);
  float rstd = rsqrtf(tot * (1.f / HID_) + 1e-5f);
  float wv[8];
  #pragma unroll
  for (int i = 0; i < 2; ++i) {
    float4 t = *(const float4*)(wn + tid * 8 + i * 4);
    wv[i * 4 + 0] = t.x; wv[i * 4 + 1] = t.y; wv[i * 4 + 2] = t.z; wv[i * 4 + 3] = t.w;
  }
  float ov[8];
  #pragma unroll
  for (int j = 0; j < 8; ++j) ov[j] = vx[j] * rstd * wv[j];
  *(uint4*)(o + (size_t)r * HID_ + tid * 8) = f8tobf(ov);
}

// fused: x2 = x + rs1 * rmsnorm(sig(gate)*ao, w1); then xq(i8) = int8quant(rmsnorm(x2, w2))
__global__ __launch_bounds__(256) void resid1_rms2(const float* __restrict__ x, const u16* __restrict__ ao,
    const float* __restrict__ gatep, const float* __restrict__ w1, const float* __restrict__ rsp,
    const float* __restrict__ w2, float* __restrict__ x2, char* __restrict__ xq, float* __restrict__ xs1) {
  __shared__ float red[4];
  const int r = blockIdx.x, tid = threadIdx.x;
  const float g = sigmoidf_(gatep[0]);
  const float rs = rsp[0];
  uint4 av = *(const uint4*)(ao + (size_t)r * HID_ + tid * 8);
  float f[8]; bf8tof(av, f);
  float ss = 0.f;
  #pragma unroll
  for (int j = 0; j < 8; ++j) { f[j] *= g; ss += f[j] * f[j]; }
  float tot = block_sum(ss, red, 4);
  float rstd1 = rsqrtf(tot * (1.f / HID_) + 1e-5f);
  const float* xr = x + (size_t)r * HID_;
  float xv2[8];
  #pragma unroll
  for (int i = 0; i < 2; ++i) {
    float4 xv = *(const float4*)(xr + tid * 8 + i * 4);
    float4 wv = *(const float4*)(w1 + tid * 8 + i * 4);
    xv2[i * 4 + 0] = xv.x + rs * f[i * 4 + 0] * rstd1 * wv.x;
    xv2[i * 4 + 1] = xv.y + rs * f[i * 4 + 1] * rstd1 * wv.y;
    xv2[i * 4 + 2] = xv.z + rs * f[i * 4 + 2] * rstd1 * wv.z;
    xv2[i * 4 + 3] = xv.w + rs * f[i * 4 + 3] * rstd1 * wv.w;
  }
  float* o = x2 + (size_t)r * HID_;
  *(float4*)(o + tid * 8) = float4{xv2[0], xv2[1], xv2[2], xv2[3]};
  *(float4*)(o + tid * 8 + 4) = float4{xv2[4], xv2[5], xv2[6], xv2[7]};
  float ss2 = 0.f;
  #pragma unroll
  for (int j = 0; j < 8; ++j) ss2 += xv2[j] * xv2[j];
  float tot2 = block_sum(ss2, red, 4);
  float rstd2 = rsqrtf(tot2 * (1.f / HID_) + 1e-5f);
  float xn[8]; float mx = 0.f;
  #pragma unroll
  for (int i = 0; i < 2; ++i) {
    float4 wv = *(const float4*)(w2 + tid * 8 + i * 4);
    xn[i * 4 + 0] = xv2[i * 4 + 0] * rstd2 * wv.x;
    xn[i * 4 + 1] = xv2[i * 4 + 1] * rstd2 * wv.y;
    xn[i * 4 + 2] = xv2[i * 4 + 2] * rstd2 * wv.z;
    xn[i * 4 + 3] = xv2[i * 4 + 3] * rstd2 * wv.w;
  }
  #pragma unroll
  for (int j = 0; j < 8; ++j) mx = fmaxf(mx, fabsf(xn[j]));
  float bm = block_max(mx, red, 4);
  float xs = 127.f / fmaxf(bm, 1e-5f);
  float q[8];
  #pragma unroll
  for (int j = 0; j < 8; ++j) q[j] = fminf(fmaxf(rintf(xn[j] * xs), -128.f), 127.f);
  uint2 pw;
  pw.x = pk4i8(q[0], q[1], q[2], q[3]);
  pw.y = pk4i8(q[4], q[5], q[6], q[7]);
  *(uint2*)(xq + (size_t)r * HID_ + tid * 8) = pw;
  if (tid == 0) xs1[r] = xs;
}

// quantize h (silu*value) rows of 8192: bf16 in -> i8 out
__global__ __launch_bounds__(256) void quant_h_i8(const u16* __restrict__ hb, char* __restrict__ hq, float* __restrict__ xs2) {
  __shared__ float red[4];
  const int r = blockIdx.x, tid = threadIdx.x;
  const u16* hr = hb + (size_t)r * INTER_ + tid * 32;
  float f[32];
  #pragma unroll
  for (int k = 0; k < 4; ++k) {
    uint4 v = *(const uint4*)(hr + k * 8);
    bf8tof(v, &f[k * 8]);
  }
  float mx = 0.f;
  #pragma unroll
  for (int j = 0; j < 32; ++j) mx = fmaxf(mx, fabsf(f[j]));
  float bm = block_max(mx, red, 4);
  float xs = 127.f / fmaxf(bm, 1e-5f);
  u32 pw[8];
  #pragma unroll
  for (int k = 0; k < 8; ++k) {
    float q[4];
    #pragma unroll
    for (int j = 0; j < 4; ++j) q[j] = fminf(fmaxf(rintf(f[k * 4 + j] * xs), -128.f), 127.f);
    pw[k] = pk4i8(q[0], q[1], q[2], q[3]);
  }
  char* oq = hq + (size_t)r * INTER_ + tid * 32;
  *(uint4*)oq = uint4{pw[0], pw[1], pw[2], pw[3]};
  *(uint4*)(oq + 16) = uint4{pw[4], pw[5], pw[6], pw[7]};
  if (tid == 0) xs2[r] = xs;
}

// final: out = x2 + rs * rmsnorm(mlp, w)
__global__ __launch_bounds__(256) void final_resid(const float* __restrict__ x2, const u16* __restrict__ mlp,
    const float* __restrict__ wn, const float* __restrict__ rsp, float* __restrict__ out) {
  __shared__ float red[4];
  const int r = blockIdx.x, tid = threadIdx.x;
  const float rs = rsp[0];
  uint4 mv = *(const uint4*)(mlp + (size_t)r * HID_ + tid * 8);
  float f[8]; bf8tof(mv, f);
  float ss = 0.f;
  #pragma unroll
  for (int j = 0; j < 8; ++j) ss += f[j] * f[j];
  float tot = block_sum(ss, red, 4);
  float rstd = rsqrtf(tot * (1.f / HID_) + 1e-5f);
  const float* xr = x2 + (size_t)r * HID_;
  float* o = out + (size_t)r * HID_;
  #pragma unroll
  for (int i = 0; i < 2; ++i) {
    float4 xv = *(const float4*)(xr + tid * 8 + i * 4);
    float4 wv = *(const float4*)(wn + tid * 8 + i * 4);
    float4 ov;
    ov.x = xv.x + rs * f[i * 4 + 0] * rstd * wv.x;
    ov.y = xv.y + rs * f[i * 4 + 1] * rstd * wv.y;
    ov.z = xv.z + rs * f[i * 4 + 2] * rstd * wv.z;
    ov.w = xv.w + rs * f[i * 4 + 3] * rstd * wv.w;
    *(float4*)(o + tid * 8 + i * 4) = ov;
  }
}

// ---------- GEMM (bf16): C[M,*] = A[M,K] * B[N,K]^T ----------
// Round-10 proven config: 128x256 tile, 512 thr / 8 waves (2M x 4N), BK=64,
// both-sides XOR swizzle, flat grid + bijective XCD chunking, bn-fastest.
template<int NBN>
__global__ __launch_bounds__(512, 2)
void gemm_bt2(const u16* __restrict__ A, const u16* __restrict__ Bw, u16* __restrict__ C,
              int K, int ldc) {
  __shared__ __align__(16) u16 As[128 * 64];
  __shared__ __align__(16) u16 Bs[256 * 64];
  const int tid = threadIdx.x;
  const int w = tid >> 6, lane = tid & 63;
  const int l15 = lane & 15, l4 = lane >> 4;
  const int wr = (w >> 2) * 64, wc = (w & 3) * 64;
  int id = blockIdx.x;
  const int cpx = (int)gridDim.x >> 3;
  id = (id & 7) * cpx + (id >> 3);
  const int bm = id / NBN, bn = id % NBN;
  const u16* Ag = A + (size_t)bm * 128 * K;
  const u16* Bg = Bw + (size_t)bn * 256 * K;
  f32x4 acc[4][4] = {};
  for (int kk = 0; kk < K; kk += 64) {
    #pragma unroll
    for (int p = 0; p < 2; ++p) {
      const int idx = tid + p * 512;
      const int row = idx >> 3, slot = idx & 7;
      const int ss = slot ^ (row & 7);
      gload16(Ag + (size_t)row * K + kk + ss * 8, &As[idx * 8]);
    }
    #pragma unroll
    for (int p = 0; p < 4; ++p) {
      const int idx = tid + p * 512;
      const int row = idx >> 3, slot = idx & 7;
      const int ss = slot ^ (row & 7);
      gload16(Bg + (size_t)row * K + kk + ss * 8, &Bs[idx * 8]);
    }
    __syncthreads();
    bf16x8 af[4][2], bb[4][2];
    #pragma unroll
    for (int i = 0; i < 4; ++i) {
      const int ra = wr + i * 16 + l15;
      const int rb = wc + i * 16 + l15;
      #pragma unroll
      for (int k2 = 0; k2 < 2; ++k2) {
        const int g8 = k2 * 4 + l4;
        af[i][k2] = ldfrag(&As[ra * 64 + ((g8 ^ (ra & 7)) * 8)]);
        bb[i][k2] = ldfrag(&Bs[rb * 64 + ((g8 ^ (rb & 7)) * 8)]);
      }
    }
    #pragma unroll
    for (int i = 0; i < 4; ++i)
      #pragma unroll
      for (int j = 0; j < 4; ++j)
        #pragma unroll
        for (int k2 = 0; k2 < 2; ++k2)
          acc[i][j] = __builtin_amdgcn_mfma_f32_16x16x32_bf16(af[i][k2], bb[j][k2], acc[i][j], 0, 0, 0);
    __syncthreads();
  }
  #pragma unroll
  for (int i = 0; i < 4; ++i) {
    #pragma unroll
    for (int r = 0; r < 4; ++r) {
      const int row = bm * 128 + wr + i * 16 + l4 * 4 + r;
      #pragma unroll
      for (int j = 0; j < 4; ++j) {
        const int col = bn * 256 + wc + j * 16 + l15;
        C[(size_t)row * ldc + col] = f2bf(acc[i][j][r]);
      }
    }
  }
}

// ---------- FFN GEMMs: i8 MFMA, BK=128, both-sides XOR swizzle ----------
__global__ __launch_bounds__(512, 2)
void gemm_up_i8(const char* __restrict__ A, const char* __restrict__ Bw, u16* __restrict__ H,
                const float* __restrict__ wsp, const float* __restrict__ xs) {
  const int K = HID_;
  __shared__ __align__(16) char As[128 * 128];
  __shared__ __align__(16) char Gs[128 * 128];
  __shared__ __align__(16) char Vs[128 * 128];
  const int tid = threadIdx.x;
  const int w = tid >> 6, lane = tid & 63;
  const int l15 = lane & 15, l4 = lane >> 4;
  const int wr = (w >> 2) * 64, wc = (w & 3) * 32;
  int id = blockIdx.x;
  const int cpx = (int)gridDim.x >> 3;
  id = (id & 7) * cpx + (id >> 3);
  const int bm = id & 31, bn = id >> 5;
  const char* Ag = A + (size_t)bm * 128 * K;
  const char* Gg = Bw + (size_t)bn * 128 * K;
  const char* Vg = Bw + ((size_t)INTER_ + bn * 128) * K;
  i32x4 ag[4][2] = {}, av[4][2] = {};
  for (int kk = 0; kk < K; kk += 128) {
    #pragma unroll
    for (int p = 0; p < 2; ++p) {
      const int idx = tid + p * 512;
      const int row = idx >> 3, slot = idx & 7;
      const int ss = slot ^ (row & 7);
      gload16(Ag + (size_t)row * K + kk + ss * 16, &As[idx * 16]);
      gload16(Gg + (size_t)row * K + kk + ss * 16, &Gs[idx * 16]);
      gload16(Vg + (size_t)row * K + kk + ss * 16, &Vs[idx * 16]);
    }
    __syncthreads();
    i32x4 af_[4][2], gf_[2][2], vf_[2][2];
    #pragma unroll
    for (int i = 0; i < 4; ++i) {
      const int r = wr + i * 16 + l15;
      #pragma unroll
      for (int k2 = 0; k2 < 2; ++k2) {
        const int j = k2 * 4 + l4;
        af_[i][k2] = *(const i32x4*)&As[r * 128 + ((j ^ (r & 7)) * 16)];
      }
    }
    #pragma unroll
    for (int jj = 0; jj < 2; ++jj) {
      const int r = wc + jj * 16 + l15;
      #pragma unroll
      for (int k2 = 0; k2 < 2; ++k2) {
        const int j = k2 * 4 + l4;
        gf_[jj][k2] = *(const i32x4*)&Gs[r * 128 + ((j ^ (r & 7)) * 16)];
        vf_[jj][k2] = *(const i32x4*)&Vs[r * 128 + ((j ^ (r & 7)) * 16)];
      }
    }
    #pragma unroll
    for (int i = 0; i < 4; ++i)
      #pragma unroll
      for (int jj = 0; jj < 2; ++jj)
        #pragma unroll
        for (int k2 = 0; k2 < 2; ++k2) {
          ag[i][jj] = __builtin_amdgcn_mfma_i32_16x16x64_i8(af_[i][k2], gf_[jj][k2], ag[i][jj], 0, 0, 0);
          av[i][jj] = __builtin_amdgcn_mfma_i32_16x16x64_i8(af_[i][k2], vf_[jj][k2], av[i][jj], 0, 0, 0);
        }
    __syncthreads();
  }
  const float ws0 = wsp[0];
  #pragma unroll
  for (int i = 0; i < 4; ++i) {
    #pragma unroll
    for (int r = 0; r < 4; ++r) {
      const int row = bm * 128 + wr + i * 16 + l4 * 4 + r;
      const float scl = ws0 / xs[row];
      #pragma unroll
      for (int jj = 0; jj < 2; ++jj) {
        const int col = bn * 128 + wc + jj * 16 + l15;
        const float og = (float)ag[i][jj][r] * scl;
        const float ov = (float)av[i][jj][r] * scl;
        const float hv = og * ov / (1.f + expf(-og));  // silu(og)*ov
        H[(size_t)row * INTER_ + col] = f2bf(hv);
      }
    }
  }
}

// down-proj (round-8 proven config): 256 thr, 128x128 tile, grid dim3(16,32) bn-fastest
__global__ __launch_bounds__(256, 2)
void gemm_dn_i8(const char* __restrict__ A, const char* __restrict__ Bw, u16* __restrict__ C,
                const float* __restrict__ wsp, const float* __restrict__ xs) {
  const int N = HID_, K = INTER_;
  __shared__ __align__(16) char As[128 * 128];
  __shared__ __align__(16) char Bs[128 * 128];
  const int tid = threadIdx.x;
  const int wv = tid >> 6, lane = tid & 63;
  const int l15 = lane & 15, l4 = lane >> 4;
  const int wr = (wv >> 1) * 64, wc = (wv & 1) * 64;
  const int bm = blockIdx.y, bn = blockIdx.x;
  const char* Ag = A + (size_t)bm * 128 * K;
  const char* Bg = Bw + (size_t)bn * 128 * K;
  i32x4 acc[4][4] = {};
  for (int kk = 0; kk < K; kk += 128) {
    #pragma unroll
    for (int p = 0; p < 4; ++p) {
      const int idx = tid + p * 256;
      const int row = idx >> 3, slot = idx & 7;
      const int ss = slot ^ (row & 7);
      gload16(Ag + (size_t)row * K + kk + ss * 16, &As[idx * 16]);
      gload16(Bg + (size_t)row * K + kk + ss * 16, &Bs[idx * 16]);
    }
    __syncthreads();
    i32x4 af_[4][2], bb_[4][2];
    #pragma unroll
    for (int i = 0; i < 4; ++i) {
      const int ra = wr + i * 16 + l15;
      const int rb = wc + i * 16 + l15;
      #pragma unroll
      for (int k2 = 0; k2 < 2; ++k2) {
        const int j = k2 * 4 + l4;
        af_[i][k2] = *(const i32x4*)&As[ra * 128 + ((j ^ (ra & 7)) * 16)];
        bb_[i][k2] = *(const i32x4*)&Bs[rb * 128 + ((j ^ (rb & 7)) * 16)];
      }
    }
    #pragma unroll
    for (int i = 0; i < 4; ++i)
      #pragma unroll
      for (int j = 0; j < 4; ++j)
        #pragma unroll
        for (int k2 = 0; k2 < 2; ++k2)
          acc[i][j] = __builtin_amdgcn_mfma_i32_16x16x64_i8(af_[i][k2], bb_[j][k2], acc[i][j], 0, 0, 0);
    __syncthreads();
  }
  const float ws0 = wsp[0];
  #pragma unroll
  for (int i = 0; i < 4; ++i) {
    #pragma unroll
    for (int r = 0; r < 4; ++r) {
      const int row = bm * 128 + wr + i * 16 + l4 * 4 + r;
      const float scl = ws0 / xs[row];
      #pragma unroll
      for (int j = 0; j < 4; ++j) {
        const int col = bn * 128 + wc + j * 16 + l15;
        C[(size_t)row * N + col] = f2bf((float)acc[i][j][r] * scl);
      }
    }
  }
}

// ---------- attention (MFMA); q/k/v are column slices of fused qkv (row stride ldq) ----------
DEV void write_otile(const f32x16 oc, float invl, char* stgB, u16* alocrow,
                     int da, int l31, int hi, int lane) {
  #pragma unroll
  for (int r = 0; r < 16; ++r) {
    const int dl = (r & 3) + 8 * (r >> 2) + 4 * hi;
    *(u16*)(stgB + l31 * 64 + ((dl * 2) ^ ((l31 & 3) << 4))) = f2bf(oc[r] * invl);
  }
  #pragma unroll
  for (int p = 0; p < 2; ++p) {
    const int s = lane >> 1;
    const int d8 = (lane & 1) * 8 + p * 16;
    const uint4 val = *(const uint4*)(stgB + s * 64 + ((d8 * 2) ^ ((s & 3) << 4)));
    *(uint4*)(alocrow + (size_t)s * HD_ + da * 32 + d8) = val;
  }
}

__global__ __launch_bounds__(512)
void attn_local_mfma(const u16* __restrict__ q, const u16* __restrict__ k, const u16* __restrict__ v,
                     u16* __restrict__ aloc, float* __restrict__ Useg, float* __restrict__ yseg, int ldq) {
  __shared__ __align__(16) u16 Ks[512 * 64];
  __shared__ __align__(16) u16 VT[64 * 512];
  __shared__ __align__(16) u16 SP[9216];
  const int bid = blockIdx.x;
  const int c = bid >> 7, bh = bid & 127;
  const int b = bh >> 5, h = bh & 31;
  const int tid = threadIdx.x, w = tid >> 6, lane = tid & 63;
  const int l31 = lane & 31, hi = lane >> 5;
  const size_t rowbase = ((size_t)b * S_ + c * SEG_) * (size_t)ldq + h * HD_;
  const u16* qg = q + rowbase;
  const u16* kg = k + rowbase;
  const u16* vg = v + rowbase;
  char* KsB = (char*)Ks;
  char* VTB = (char*)VT;
  #pragma unroll
  for (int p = 0; p < 8; ++p) {
    const int idx = tid + p * 512;
    const int t = idx >> 3, dg = idx & 7;
    const uint4 kv = *(const uint4*)(kg + (size_t)t * ldq + dg * 8);
    *(uint4*)(KsB + t * 128 + ((dg * 16) ^ ((t & 7) << 4))) = kv;
  }
  {
    const int t = w * 64 + lane;
    #pragma unroll
    for (int dg = 0; dg < 8; ++dg) {
      const uint4 vv = *(const uint4*)(vg + (size_t)t * ldq + dg * 8);
      const u16* e = (const u16*)&vv;
      #pragma unroll
      for (int j = 0; j < 8; ++j) {
        const int d = dg * 8 + j;
        *(u16*)(VTB + d * 1024 + ((t * 2) ^ ((d & 7) << 4))) = e[j];
      }
    }
  }
  // balanced wave->q-tile map: wave w owns tiles {w, 15-w} (17 t-block iters each)
  uint4 qf[2][4];
  #pragma unroll
  for (int qi = 0; qi < 2; ++qi) {
    const int qt = qi == 0 ? w : 15 - w;
    #pragma unroll
    for (int ks = 0; ks < 4; ++ks)
      qf[qi][ks] = *(const uint4*)(qg + (size_t)(qt * 32 + l31) * ldq + ks * 16 + hi * 8);
  }
  __syncthreads();

  const size_t arow = (size_t)(b * NH_ + h) * S_ + c * SEG_;
  const int swzk = (l31 & 7) << 4;
  char* stgB = (char*)SP + w * 2048;
  #pragma unroll
  for (int qi = 0; qi < 2; ++qi) {
    const int qt = qi == 0 ? w : 15 - w;
    f32x16 o0 = {}, o1 = {};
    float m = -3e38f, l = 0.f;
    const int nb = qt + 1;
    for (int tb = 0; tb < nb; ++tb) {
      f32x16 st = {};
      #pragma unroll
      for (int ks = 0; ks < 4; ++ks) {
        const uint4 ka = *(const uint4*)(KsB + (tb * 32 + l31) * 128 + (((ks * 16 + hi * 8) * 2) ^ swzk));
        st = __builtin_amdgcn_mfma_f32_32x32x16_bf16(__builtin_bit_cast(bf16x8, ka),
                                                     __builtin_bit_cast(bf16x8, qf[qi][ks]), st, 0, 0, 0);
      }
      if (tb == nb - 1) {
        #pragma unroll
        for (int r = 0; r < 16; ++r) {
          const int tl = (r & 3) + 8 * (r >> 2) + 4 * hi;
          if (tl > l31) st[r] = -3e38f;
        }
      }
      float tm = st[0];
      #pragma unroll
      for (int r = 1; r < 16; ++r) tm = fmaxf(tm, st[r]);
      tm = fmaxf(tm, __shfl_xor(tm, 32, 64));
      const float mn = fmaxf(m, tm);
      const float fac = __expf((m - mn) * 0.125f);
      float pr[16]; float ps = 0.f;
      #pragma unroll
      for (int r = 0; r < 16; ++r) { pr[r] = __expf((st[r] - mn) * 0.125f); ps += pr[r]; }
      ps += __shfl_xor(ps, 32, 64);
      l = l * fac + ps;
      m = mn;
      #pragma unroll
      for (int r = 0; r < 16; ++r) { o0[r] *= fac; o1[r] *= fac; }
      #pragma unroll
      for (int c2 = 0; c2 < 2; ++c2) {
        const int bi = c2 * 8;
        const u32 a0 = pkbf(pr[bi + 0], pr[bi + 1]);
        const u32 a1 = pkbf(pr[bi + 2], pr[bi + 3]);
        const u32 a2 = pkbf(pr[bi + 4], pr[bi + 5]);
        const u32 a3 = pkbf(pr[bi + 6], pr[bi + 7]);
        const u32 x0 = (u32)__shfl_xor((int)a0, 32, 64);
        const u32 x1 = (u32)__shfl_xor((int)a1, 32, 64);
        const u32 x2 = (u32)__shfl_xor((int)a2, 32, 64);
        const u32 x3 = (u32)__shfl_xor((int)a3, 32, 64);
        uint4 pw;
        pw.x = hi ? x2 : a0;
        pw.y = hi ? x3 : a1;
        pw.z = hi ? a2 : x0;
        pw.w = hi ? a3 : x1;
        const bf16x8 pfr = __builtin_bit_cast(bf16x8, pw);
        const int tO = (tb * 32 + c2 * 16 + hi * 8) * 2;
        const uint4 v0 = *(const uint4*)(VTB + l31 * 1024 + (tO ^ swzk));
        const uint4 v1 = *(const uint4*)(VTB + (32 + l31) * 1024 + (tO ^ swzk));
        o0 = __builtin_amdgcn_mfma_f32_32x32x16_bf16(__builtin_bit_cast(bf16x8, v0), pfr, o0, 0, 0, 0);
        o1 = __builtin_amdgcn_mfma_f32_32x32x16_bf16(__builtin_bit_cast(bf16x8, v1), pfr, o1, 0, 0, 0);
      }
    }
    const float invl = 1.f / l;
    u16* alocrow = aloc + (arow + qt * 32) * HD_;
    write_otile(o0, invl, stgB, alocrow, 0, l31, hi, lane);
    write_otile(o1, invl, stgB, alocrow, 1, l31, hi, lane);
  }

  __syncthreads();
  float* Ured = (float*)SP;
  float* yred = (float*)((char*)SP + 16384);
  for (int i = tid; i < 4096; i += 512) Ured[i] = 0.f;
  yred[tid] = 0.f;
  __syncthreads();
  f32x16 u00 = {}, u01 = {}, u10 = {}, u11 = {};
  float y0 = 0.f, y1 = 0.f;
  #pragma unroll
  for (int kc = 0; kc < 4; ++kc) {
    const int t0 = w * 64 + kc * 16 + hi * 8;
    uint4 af[2];
    #pragma unroll
    for (int da2 = 0; da2 < 2; ++da2) {
      const int d = da2 * 32 + l31;
      u32 wds[4];
      #pragma unroll
      for (int jp = 0; jp < 4; ++jp) {
        const int ta = t0 + jp * 2;
        const int tb2 = ta + 1;
        const float kfa = bf2f(*(const u16*)(KsB + ta * 128 + ((d * 2) ^ ((ta & 7) << 4))));
        const float kfb = bf2f(*(const u16*)(KsB + tb2 * 128 + ((d * 2) ^ ((tb2 & 7) << 4))));
        const float sa = kfa > 0.f ? kfa + 1.f : __expf(kfa);
        const float sb = kfb > 0.f ? kfb + 1.f : __expf(kfb);
        if (da2 == 0) y0 += sa + sb; else y1 += sa + sb;
        wds[jp] = pkbf(sa, sb);
      }
      af[da2].x = wds[0]; af[da2].y = wds[1]; af[da2].z = wds[2]; af[da2].w = wds[3];
    }
    const int tO = t0 * 2;
    const uint4 vb0 = *(const uint4*)(VTB + l31 * 1024 + (tO ^ swzk));
    const uint4 vb1 = *(const uint4*)(VTB + (32 + l31) * 1024 + (tO ^ swzk));
    const bf16x8 a0f = __builtin_bit_cast(bf16x8, af[0]);
    const bf16x8 a1f = __builtin_bit_cast(bf16x8, af[1]);
    const bf16x8 b0f = __builtin_bit_cast(bf16x8, vb0);
    const bf16x8 b1f = __builtin_bit_cast(bf16x8, vb1);
    u00 = __builtin_amdgcn_mfma_f32_32x32x16_bf16(a0f, b0f, u00, 0, 0, 0);
    u01 = __builtin_amdgcn_mfma_f32_32x32x16_bf16(a0f, b1f, u01, 0, 0, 0);
    u10 = __builtin_amdgcn_mfma_f32_32x32x16_bf16(a1f, b0f, u10, 0, 0, 0);
    u11 = __builtin_amdgcn_mfma_f32_32x32x16_bf16(a1f, b1f, u11, 0, 0, 0);
  }
  y0 += __shfl_xor(y0, 32, 64);
  y1 += __shfl_xor(y1, 32, 64);
  if (hi == 0) { yred[w * 64 + l31] = y0; yred[w * 64 + 32 + l31] = y1; }
  for (int ww = 0; ww < 8; ++ww) {
    if (w == ww) {
      #pragma unroll
      for (int r = 0; r < 16; ++r) {
        const int dl = (r & 3) + 8 * (r >> 2) + 4 * hi;
        Ured[dl * 64 + l31]            += u00[r];
        Ured[dl * 64 + 32 + l31]       += u01[r];
        Ured[(32 + dl) * 64 + l31]     += u10[r];
        Ured[(32 + dl) * 64 + 32 + l31]+= u11[r];
      }
    }
    __syncthreads();
  }
  float* Ug = Useg + (size_t)(c * 128 + bh) * 4096;
  for (int i = tid; i < 4096; i += 512) Ug[i] = Ured[i];
  if (tid < 64) {
    float a2 = 0.f;
    #pragma unroll
    for (int ww = 0; ww < 8; ++ww) a2 += yred[ww * 64 + tid];
    yseg[(size_t)(c * 128 + bh) * 64 + tid] = a2;
  }
}

__global__ __launch_bounds__(256)
void attn_prefix(const float* __restrict__ Useg, const float* __restrict__ yseg,
                 float* __restrict__ Mpre, float* __restrict__ zpre) {
  const int bh = blockIdx.x, tid = threadIdx.x;
  for (int idx = tid; idx < 4096; idx += 256) {
    float a2 = 0.f;
    #pragma unroll
    for (int c = 0; c < 8; ++c) {
      const size_t o = ((size_t)(c * 128 + bh)) * 4096 + idx;
      Mpre[o] = a2;
      a2 += Useg[o];
    }
  }
  if (tid < 64) {
    float a2 = 0.f;
    #pragma unroll
    for (int c = 0; c < 8; ++c) {
      const size_t o = ((size_t)(c * 128 + bh)) * 64 + tid;
      zpre[o] = a2;
      a2 += yseg[o];
    }
  }
}

__global__ __launch_bounds__(512)
void attn_combine(const u16* __restrict__ q, const u16* __restrict__ aloc,
                  const float* __restrict__ Mpre, const float* __restrict__ zpre,
                  const float* __restrict__ beta, u16* __restrict__ attno, int ldq) {
  __shared__ __align__(16) u16 MbT[64 * 64];
  __shared__ float z_lds[64];
  __shared__ float amem[8][16 * 65];
  const int bid = blockIdx.x;
  const int c = bid >> 7, bh = bid & 127;
  const int b = bh >> 5, h = bh & 31;
  const int tid = threadIdx.x, w = tid >> 6, lane = tid & 63;
  const int l15 = lane & 15, l4 = lane >> 4;
  const size_t pre = (size_t)(c * 128 + bh);
  char* MbB = (char*)MbT;
  for (int i = tid; i < 4096; i += 512) {
    const int d = i >> 6, e = i & 63;
    *(u16*)(MbB + (((e * 64 + d) * 2) ^ ((e & 7) << 4))) = f2bf(Mpre[pre * 4096 + i]);
  }
  if (tid < 64) z_lds[tid] = zpre[pre * 64 + tid];
  __syncthreads();
  bf16x8 bb[2][4];
  #pragma unroll
  for (int ks = 0; ks < 2; ++ks)
    #pragma unroll
    for (int jt = 0; jt < 4; ++jt) {
      const int e = jt * 16 + l15;
      const uint4 u = *(const uint4*)(MbB + (((e * 64 + ks * 32 + l4 * 8) * 2) ^ ((e & 7) << 4)));
      bb[ks][jt] = __builtin_bit_cast(bf16x8, u);
    }
  const float g = sigmoidf_(beta[h]);
  const float og = 1.f - g;
  const u16* qg = q + ((size_t)b * S_ + c * SEG_) * ldq + h * HD_;
  const size_t arow = (size_t)(b * NH_ + h) * S_ + c * SEG_;
  u16* orow = attno + ((size_t)b * S_ + c * SEG_) * HID_ + h * HD_;
  const int rr = lane >> 2, cq = (lane & 3) * 16;
  #pragma unroll
  for (int mi = 0; mi < 4; ++mi) {
    const int s0 = w * 64 + mi * 16;
    f32x4 acc[4] = {};
    float pd = 0.f;
    #pragma unroll
    for (int ks = 0; ks < 2; ++ks) {
      const uint4 qv = *(const uint4*)(qg + (size_t)(s0 + l15) * ldq + ks * 32 + l4 * 8);
      float f[8]; bf8tof(qv, f);
      float sq[8];
      #pragma unroll
      for (int j = 0; j < 8; ++j) {
        sq[j] = f[j] > 0.f ? f[j] + 1.f : __expf(f[j]);
        pd = fmaf(sq[j], z_lds[ks * 32 + l4 * 8 + j], pd);
      }
      uint4 pw;
      pw.x = pkbf(sq[0], sq[1]); pw.y = pkbf(sq[2], sq[3]);
      pw.z = pkbf(sq[4], sq[5]); pw.w = pkbf(sq[6], sq[7]);
      const bf16x8 af = __builtin_bit_cast(bf16x8, pw);
      #pragma unroll
      for (int jt = 0; jt < 4; ++jt)
        acc[jt] = __builtin_amdgcn_mfma_f32_16x16x32_bf16(af, bb[ks][jt], acc[jt], 0, 0, 0);
    }
    pd += __shfl_xor(pd, 16, 64);
    pd += __shfl_xor(pd, 32, 64);
    pd += 1e-6f;
    float dinv[4];
    #pragma unroll
    for (int r = 0; r < 4; ++r) dinv[r] = 1.f / __shfl(pd, l4 * 4 + r, 64);
    #pragma unroll
    for (int jt = 0; jt < 4; ++jt)
      #pragma unroll
      for (int r = 0; r < 4; ++r)
        amem[w][(l4 * 4 + r) * 65 + jt * 16 + l15] = acc[jt][r] * dinv[r];
    const int s = s0 + rr;
    const u16* alr = aloc + (arow + s) * HD_ + cq;
    const uint4 a0 = *(const uint4*)alr;
    const uint4 a1 = *(const uint4*)(alr + 8);
    float alf[16];
    bf8tof(a0, alf); bf8tof(a1, alf + 8);
    float ov[16];
    #pragma unroll
    for (int t = 0; t < 16; ++t)
      ov[t] = g * amem[w][rr * 65 + cq + t] + og * alf[t];
    *(uint4*)(orow + (size_t)s * HID_ + cq) = f8tobf(ov);
    *(uint4*)(orow + (size_t)s * HID_ + cq + 8) = f8tobf(ov + 8);
  }
}

// ---------- launch ----------
extern "C" void kernel_launch(void* const* d_in, const int* in_sizes, int n_in,
                              void* d_out, int out_size, void* d_ws, size_t ws_size,
                              hipStream_t stream) {
  const float* x    = (const float*)d_in[0];
  const float* wq   = (const float*)d_in[1];
  const float* wk   = (const float*)d_in[2];
  const float* wv   = (const float*)d_in[3];
  const float* wo   = (const float*)d_in[4];
  const float* beta = (const float*)d_in[5];
  const float* gate = (const float*)d_in[6];
  const float* anw  = (const float*)d_in[7];
  const float* mnw  = (const float*)d_in[8];
  const float* arnw = (const float*)d_in[9];
  const float* arsc = (const float*)d_in[10];
  const float* mrnw = (const float*)d_in[11];
  const float* mrsc = (const float*)d_in[12];
  const float* fup  = (const float*)d_in[13];
  const float* fdn  = (const float*)d_in[14];

  char* W = (char*)d_ws;
  const size_t MB = 1ull << 20;
  u16*   xn1   = (u16*)(W + 0);
  u16*   attno = (u16*)(W + 0);
  u16*   mlpb  = (u16*)(W + 0);
  u16*   qkv   = (u16*)(W + 64 * MB);
  char*  xq1   = (char*)(W + 64 * MB);
  u16*   aob   = (u16*)(W + 128 * MB);
  u16*   hbuf  = (u16*)(W + 128 * MB);
  u16*   alocb = (u16*)(W + 256 * MB);
  float* x2    = (float*)(W + 192 * MB);
  float* Useg  = (float*)(W + 320 * MB);
  float* Mpre  = (float*)(W + 336 * MB);
  float* yseg  = (float*)(W + 352 * MB);
  float* zpre  = (float*)(W + 352 * MB + 262144);
  float* xs1   = (float*)(W + 352 * MB + 524288);
  float* xs2   = (float*)(W + 352 * MB + 589824);
  float* wsu   = (float*)(W + 352 * MB + 655360);
  float* wsd   = (float*)(W + 352 * MB + 655616);
  float* partU = (float*)(W + 352 * MB + 655872);
  float* partD = (float*)(W + 352 * MB + 664064);
  u16*   w16qkv= (u16*)(W + 353 * MB);          // [6144,2048] = wq|wk|wv
  u16*   w16o  = (u16*)(W + 377 * MB);
  char*  wqup  = (char*)(W + 385 * MB);
  char*  wqdn  = (char*)(W + 417 * MB);
  char*  hq    = (char*)(W + 433 * MB);

  // weight prep
  castf2b<<<4096, 256, 0, stream>>>(wq, w16qkv);
  castf2b<<<4096, 256, 0, stream>>>(wk, w16qkv + (size_t)HID_ * HID_);
  castf2b<<<4096, 256, 0, stream>>>(wv, w16qkv + 2 * (size_t)HID_ * HID_);
  castf2b<<<4096, 256, 0, stream>>>(wo, w16o);
  absmean_part<<<2048, 256, 0, stream>>>(fup, partU);
  absmean_part<<<1024, 256, 0, stream>>>(fdn, partD);
  absmean_fin<<<1, 256, 0, stream>>>(partU, 2048, 1.f / 33554432.f, wsu);
  absmean_fin<<<1, 256, 0, stream>>>(partD, 1024, 1.f / 16777216.f, wsd);
  ternarize_i8<<<32768, 256, 0, stream>>>(fup, wsu, wqup);
  ternarize_i8<<<16384, 256, 0, stream>>>(fdn, wsd, wqdn);

  // attention path: fused QKV GEMM -> qkv[16384,6144]
  rmsnorm_cast<<<16384, 256, 0, stream>>>(x, anw, xn1);
  gemm_bt2<24><<<3072, 512, 0, stream>>>(xn1, w16qkv, qkv, HID_, LDQ_);
  attn_local_mfma<<<1024, 512, 0, stream>>>(qkv, qkv + HID_, qkv + 2 * HID_, alocb, Useg, yseg, LDQ_);
  attn_prefix<<<128, 256, 0, stream>>>(Useg, yseg, Mpre, zpre);
  attn_combine<<<1024, 512, 0, stream>>>(qkv, alocb, Mpre, zpre, beta, attno, LDQ_);
  gemm_bt2<8><<<1024, 512, 0, stream>>>(attno, w16o, aob, HID_, HID_);
  resid1_rms2<<<16384, 256, 0, stream>>>(x, aob, gate, arnw, arsc, mnw, x2, xq1, xs1);

  // MLP path (4 token-chunks of 4096 rows, i8 MFMA)
  for (int cc = 0; cc < 4; ++cc) {
    const size_t base = (size_t)cc * CHROWS_;
    gemm_up_i8<<<2048, 512, 0, stream>>>(xq1 + base * HID_, wqup, hbuf, wsu, xs1 + base);
    quant_h_i8<<<4096, 256, 0, stream>>>(hbuf, hq, xs2 + base);
    gemm_dn_i8<<<dim3(16, 32), 256, 0, stream>>>(hq, wqdn, mlpb + base * HID_, wsd, xs2 + base);
  }
  final_resid<<<16384, 256, 0, stream>>>(x2, mlpb, mrnw, mrsc, (float*)d_out);
}

// Round 13
// 1969.272 us; speedup vs baseline: 1.0550x; 1.0025x over previous
//
#include <hip/hip_runtime.h>
#include <cstdint>
#include <cstddef>

typedef unsigned int u32;
typedef unsigned short u16;
typedef __bf16 bf16x8 __attribute__((ext_vector_type(8)));
typedef float f32x4 __attribute__((ext_vector_type(4)));
typedef float f32x16 __attribute__((ext_vector_type(16)));
typedef int i32x4 __attribute__((ext_vector_type(4)));

#define DEV static __device__ __forceinline__

// ---------- helpers ----------
DEV float bf2f(u16 u) { u32 x = ((u32)u) << 16; return __builtin_bit_cast(float, x); }
DEV u16 f2bf(float f) {
  u32 u = __builtin_bit_cast(u32, f);
  u32 r = (u + 0x7fffu + ((u >> 16) & 1u)) >> 16;  // RNE
  return (u16)r;
}
DEV u32 pkbf(float a, float b) {
  __bf16 ba = (__bf16)a, bb = (__bf16)b;
  return (u32)__builtin_bit_cast(u16, ba) | ((u32)__builtin_bit_cast(u16, bb) << 16);
}
DEV u32 pk4i8(float a, float b, float c, float d) {
  return (u32)(unsigned char)(char)a | ((u32)(unsigned char)(char)b << 8) |
         ((u32)(unsigned char)(char)c << 16) | ((u32)(unsigned char)(char)d << 24);
}
DEV void bf8tof(const uint4 v, float* f) {
  f[0] = bf2f((u16)(v.x & 0xffffu)); f[1] = bf2f((u16)(v.x >> 16));
  f[2] = bf2f((u16)(v.y & 0xffffu)); f[3] = bf2f((u16)(v.y >> 16));
  f[4] = bf2f((u16)(v.z & 0xffffu)); f[5] = bf2f((u16)(v.z >> 16));
  f[6] = bf2f((u16)(v.w & 0xffffu)); f[7] = bf2f((u16)(v.w >> 16));
}
DEV uint4 f8tobf(const float* f) {
  uint4 r;
  r.x = (u32)f2bf(f[0]) | ((u32)f2bf(f[1]) << 16);
  r.y = (u32)f2bf(f[2]) | ((u32)f2bf(f[3]) << 16);
  r.z = (u32)f2bf(f[4]) | ((u32)f2bf(f[5]) << 16);
  r.w = (u32)f2bf(f[6]) | ((u32)f2bf(f[7]) << 16);
  return r;
}
DEV float sigmoidf_(float x) { return 1.f / (1.f + expf(-x)); }

DEV float wred_sum(float v) {
  #pragma unroll
  for (int m = 32; m; m >>= 1) v += __shfl_xor(v, m, 64);
  return v;
}
DEV float wred_max(float v) {
  #pragma unroll
  for (int m = 32; m; m >>= 1) v = fmaxf(v, __shfl_xor(v, m, 64));
  return v;
}
DEV float block_sum(float v, float* red, int nw) {
  v = wred_sum(v);
  int w = threadIdx.x >> 6, l = threadIdx.x & 63;
  if (l == 0) red[w] = v;
  __syncthreads();
  float t = red[0];
  for (int i = 1; i < nw; ++i) t += red[i];
  __syncthreads();
  return t;
}
DEV float block_max(float v, float* red, int nw) {
  v = wred_max(v);
  int w = threadIdx.x >> 6, l = threadIdx.x & 63;
  if (l == 0) red[w] = v;
  __syncthreads();
  float t = red[0];
  for (int i = 1; i < nw; ++i) t = fmaxf(t, red[i]);
  __syncthreads();
  return t;
}
DEV void gload16(const void* g, void* l) {
  __builtin_amdgcn_global_load_lds((const __attribute__((address_space(1))) void*)g,
                                   (__attribute__((address_space(3))) void*)l, 16, 0, 0);
}
DEV bf16x8 ldfrag(const u16* p) {
  uint4 u = *(const uint4*)p;
  return __builtin_bit_cast(bf16x8, u);
}

// ---------- constants ----------
#define BN_ 4
#define S_ 4096
#define HID_ 2048
#define NH_ 32
#define HD_ 64
#define INTER_ 8192
#define NBSEG_ 8
#define SEG_ 512
#define TOK_ 16384
#define CHROWS_ 4096   // MLP token-chunk rows
#define LDQ_ 6144      // fused qkv row stride

// ---------- elementwise / prep kernels ----------
__global__ __launch_bounds__(256) void castf2b(const float* __restrict__ a, u16* __restrict__ o) {
  size_t idx = ((size_t)blockIdx.x * 256 + threadIdx.x) * 4;
  float4 v = *(const float4*)(a + idx);
  float f[4] = {v.x, v.y, v.z, v.w};
  uint2 r;
  r.x = (u32)f2bf(f[0]) | ((u32)f2bf(f[1]) << 16);
  r.y = (u32)f2bf(f[2]) | ((u32)f2bf(f[3]) << 16);
  *(uint2*)(o + idx) = r;
}

__global__ __launch_bounds__(256) void absmean_part(const float* __restrict__ w, float* __restrict__ part) {
  __shared__ float red[4];
  size_t base = (size_t)blockIdx.x * 16384 + threadIdx.x * 4;
  float s = 0.f;
  #pragma unroll
  for (int i = 0; i < 16; ++i) {
    float4 v = *(const float4*)(w + base + (size_t)i * 1024);
    s += fabsf(v.x) + fabsf(v.y) + fabsf(v.z) + fabsf(v.w);
  }
  float t = block_sum(s, red, 4);
  if (threadIdx.x == 0) part[blockIdx.x] = t;
}

__global__ __launch_bounds__(256) void absmean_fin(const float* __restrict__ part, int n, float invN, float* __restrict__ outp) {
  __shared__ float red[4];
  float s = 0.f;
  for (int i = threadIdx.x; i < n; i += 256) s += part[i];
  float t = block_sum(s, red, 4);
  if (threadIdx.x == 0) outp[0] = t * invN + 1e-8f;
}

// ternary weights -> i8
__global__ __launch_bounds__(256) void ternarize_i8(const float* __restrict__ w, const float* __restrict__ wsp, char* __restrict__ o) {
  size_t idx = ((size_t)blockIdx.x * 256 + threadIdx.x) * 4;
  const float inv = 1.f / wsp[0];
  float4 v = *(const float4*)(w + idx);
  float q0 = rintf(fminf(fmaxf(v.x * inv, -1.f), 1.f));
  float q1 = rintf(fminf(fmaxf(v.y * inv, -1.f), 1.f));
  float q2 = rintf(fminf(fmaxf(v.z * inv, -1.f), 1.f));
  float q3 = rintf(fminf(fmaxf(v.w * inv, -1.f), 1.f));
  *(u32*)(o + idx) = pk4i8(q0, q1, q2, q3);
}

__global__ __launch_bounds__(256) void rmsnorm_cast(const float* __restrict__ x, const float* __restrict__ wn, u16* __restrict__ o) {
  __shared__ float red[4];
  const int r = blockIdx.x, tid = threadIdx.x;
  const float* xr = x + (size_t)r * HID_;
  float vx[8];
  #pragma unroll
  for (int i = 0; i < 2; ++i) {
    float4 t = *(const float4*)(xr + tid * 8 + i * 4);
    vx[i * 4 + 0] = t.x; vx[i * 4 + 1] = t.y; vx[i * 4 + 2] = t.z; vx[i * 4 + 3] = t.w;
  }
  float ss = 0.f;
  #pragma unroll
  for (int j = 0; j < 8; ++j) ss += vx[j] * vx[j];
  float tot = block_sum(ss, red, 4);
  float rstd = rsqrtf(tot * (1.f / HID_) + 1e-5f);
  float wv[8];
  #pragma unroll
  for (int i = 0; i < 2; ++i) {
    float4 t = *(const float4*)(wn + tid * 8 + i * 4);
    wv[i * 4 + 0] = t.x; wv[i * 4 + 1] = t.y; wv[i * 4 + 2] = t.z; wv[i * 4 + 3] = t.w;
  }
  float ov[8];
  #pragma unroll
  for (int j = 0; j < 8; ++j) ov[j] = vx[j] * rstd * wv[j];
  *(uint4*)(o + (size_t)r * HID_ + tid * 8) = f8tobf(ov);
}

// fused: x2 = x + rs1 * rmsnorm(sig(gate)*ao, w1); then xq(i8) = int8quant(rmsnorm(x2, w2))
__global__ __launch_bounds__(256) void resid1_rms2(const float* __restrict__ x, const u16* __restrict__ ao,
    const float* __restrict__ gatep, const float* __restrict__ w1, const float* __restrict__ rsp,
    const float* __restrict__ w2, float* __restrict__ x2, char* __restrict__ xq, float* __restrict__ xs1) {
  __shared__ float red[4];
  const int r = blockIdx.x, tid = threadIdx.x;
  const float g = sigmoidf_(gatep[0]);
  const float rs = rsp[0];
  uint4 av = *(const uint4*)(ao + (size_t)r * HID_ + tid * 8);
  float f[8]; bf8tof(av, f);
  float ss = 0.f;
  #pragma unroll
  for (int j = 0; j < 8; ++j) { f[j] *= g; ss += f[j] * f[j]; }
  float tot = block_sum(ss, red, 4);
  float rstd1 = rsqrtf(tot * (1.f / HID_) + 1e-5f);
  const float* xr = x + (size_t)r * HID_;
  float xv2[8];
  #pragma unroll
  for (int i = 0; i < 2; ++i) {
    float4 xv = *(const float4*)(xr + tid * 8 + i * 4);
    float4 wv = *(const float4*)(w1 + tid * 8 + i * 4);
    xv2[i * 4 + 0] = xv.x + rs * f[i * 4 + 0] * rstd1 * wv.x;
    xv2[i * 4 + 1] = xv.y + rs * f[i * 4 + 1] * rstd1 * wv.y;
    xv2[i * 4 + 2] = xv.z + rs * f[i * 4 + 2] * rstd1 * wv.z;
    xv2[i * 4 + 3] = xv.w + rs * f[i * 4 + 3] * rstd1 * wv.w;
  }
  float* o = x2 + (size_t)r * HID_;
  *(float4*)(o + tid * 8) = float4{xv2[0], xv2[1], xv2[2], xv2[3]};
  *(float4*)(o + tid * 8 + 4) = float4{xv2[4], xv2[5], xv2[6], xv2[7]};
  float ss2 = 0.f;
  #pragma unroll
  for (int j = 0; j < 8; ++j) ss2 += xv2[j] * xv2[j];
  float tot2 = block_sum(ss2, red, 4);
  float rstd2 = rsqrtf(tot2 * (1.f / HID_) + 1e-5f);
  float xn[8]; float mx = 0.f;
  #pragma unroll
  for (int i = 0; i < 2; ++i) {
    float4 wv = *(const float4*)(w2 + tid * 8 + i * 4);
    xn[i * 4 + 0] = xv2[i * 4 + 0] * rstd2 * wv.x;
    xn[i * 4 + 1] = xv2[i * 4 + 1] * rstd2 * wv.y;
    xn[i * 4 + 2] = xv2[i * 4 + 2] * rstd2 * wv.z;
    xn[i * 4 + 3] = xv2[i * 4 + 3] * rstd2 * wv.w;
  }
  #pragma unroll
  for (int j = 0; j < 8; ++j) mx = fmaxf(mx, fabsf(xn[j]));
  float bm = block_max(mx, red, 4);
  float xs = 127.f / fmaxf(bm, 1e-5f);
  float q[8];
  #pragma unroll
  for (int j = 0; j < 8; ++j) q[j] = fminf(fmaxf(rintf(xn[j] * xs), -128.f), 127.f);
  uint2 pw;
  pw.x = pk4i8(q[0], q[1], q[2], q[3]);
  pw.y = pk4i8(q[4], q[5], q[6], q[7]);
  *(uint2*)(xq + (size_t)r * HID_ + tid * 8) = pw;
  if (tid == 0) xs1[r] = xs;
}

// quantize h (silu*value) rows of 8192: bf16 in -> i8 out
__global__ __launch_bounds__(256) void quant_h_i8(const u16* __restrict__ hb, char* __restrict__ hq, float* __restrict__ xs2) {
  __shared__ float red[4];
  const int r = blockIdx.x, tid = threadIdx.x;
  const u16* hr = hb + (size_t)r * INTER_ + tid * 32;
  float f[32];
  #pragma unroll
  for (int k = 0; k < 4; ++k) {
    uint4 v = *(const uint4*)(hr + k * 8);
    bf8tof(v, &f[k * 8]);
  }
  float mx = 0.f;
  #pragma unroll
  for (int j = 0; j < 32; ++j) mx = fmaxf(mx, fabsf(f[j]));
  float bm = block_max(mx, red, 4);
  float xs = 127.f / fmaxf(bm, 1e-5f);
  u32 pw[8];
  #pragma unroll
  for (int k = 0; k < 8; ++k) {
    float q[4];
    #pragma unroll
    for (int j = 0; j < 4; ++j) q[j] = fminf(fmaxf(rintf(f[k * 4 + j] * xs), -128.f), 127.f);
    pw[k] = pk4i8(q[0], q[1], q[2], q[3]);
  }
  char* oq = hq + (size_t)r * INTER_ + tid * 32;
  *(uint4*)oq = uint4{pw[0], pw[1], pw[2], pw[3]};
  *(uint4*)(oq + 16) = uint4{pw[4], pw[5], pw[6], pw[7]};
  if (tid == 0) xs2[r] = xs;
}

// final: out = x2 + rs * rmsnorm(mlp, w)
__global__ __launch_bounds__(256) void final_resid(const float* __restrict__ x2, const u16* __restrict__ mlp,
    const float* __restrict__ wn, const float* __restrict__ rsp, float* __restrict__ out) {
  __shared__ float red[4];
  const int r = blockIdx.x, tid = threadIdx.x;
  const float rs = rsp[0];
  uint4 mv = *(const uint4*)(mlp + (size_t)r * HID_ + tid * 8);
  float f[8]; bf8tof(mv, f);
  float ss = 0.f;
  #pragma unroll
  for (int j = 0; j < 8; ++j) ss += f[j] * f[j];
  float tot = block_sum(ss, red, 4);
  float rstd = rsqrtf(tot * (1.f / HID_) + 1e-5f);
  const float* xr = x2 + (size_t)r * HID_;
  float* o = out + (size_t)r * HID_;
  #pragma unroll
  for (int i = 0; i < 2; ++i) {
    float4 xv = *(const float4*)(xr + tid * 8 + i * 4);
    float4 wv = *(const float4*)(wn + tid * 8 + i * 4);
    float4 ov;
    ov.x = xv.x + rs * f[i * 4 + 0] * rstd * wv.x;
    ov.y = xv.y + rs * f[i * 4 + 1] * rstd * wv.y;
    ov.z = xv.z + rs * f[i * 4 + 2] * rstd * wv.z;
    ov.w = xv.w + rs * f[i * 4 + 3] * rstd * wv.w;
    *(float4*)(o + tid * 8 + i * 4) = ov;
  }
}

// ---------- GEMM (bf16): C[M,*] = A[M,K] * B[N,K]^T ----------
// Round-10 proven config: 128x256 tile, 512 thr / 8 waves (2M x 4N), BK=64,
// both-sides XOR swizzle, flat grid + bijective XCD chunking, bn-fastest.
template<int NBN>
__global__ __launch_bounds__(512, 2)
void gemm_bt2(const u16* __restrict__ A, const u16* __restrict__ Bw, u16* __restrict__ C,
              int K, int ldc) {
  __shared__ __align__(16) u16 As[128 * 64];
  __shared__ __align__(16) u16 Bs[256 * 64];
  const int tid = threadIdx.x;
  const int w = tid >> 6, lane = tid & 63;
  const int l15 = lane & 15, l4 = lane >> 4;
  const int wr = (w >> 2) * 64, wc = (w & 3) * 64;
  int id = blockIdx.x;
  const int cpx = (int)gridDim.x >> 3;
  id = (id & 7) * cpx + (id >> 3);
  const int bm = id / NBN, bn = id % NBN;
  const u16* Ag = A + (size_t)bm * 128 * K;
  const u16* Bg = Bw + (size_t)bn * 256 * K;
  f32x4 acc[4][4] = {};
  for (int kk = 0; kk < K; kk += 64) {
    #pragma unroll
    for (int p = 0; p < 2; ++p) {
      const int idx = tid + p * 512;
      const int row = idx >> 3, slot = idx & 7;
      const int ss = slot ^ (row & 7);
      gload16(Ag + (size_t)row * K + kk + ss * 8, &As[idx * 8]);
    }
    #pragma unroll
    for (int p = 0; p < 4; ++p) {
      const int idx = tid + p * 512;
      const int row = idx >> 3, slot = idx & 7;
      const int ss = slot ^ (row & 7);
      gload16(Bg + (size_t)row * K + kk + ss * 8, &Bs[idx * 8]);
    }
    __syncthreads();
    bf16x8 af[4][2], bb[4][2];
    #pragma unroll
    for (int i = 0; i < 4; ++i) {
      const int ra = wr + i * 16 + l15;
      const int rb = wc + i * 16 + l15;
      #pragma unroll
      for (int k2 = 0; k2 < 2; ++k2) {
        const int g8 = k2 * 4 + l4;
        af[i][k2] = ldfrag(&As[ra * 64 + ((g8 ^ (ra & 7)) * 8)]);
        bb[i][k2] = ldfrag(&Bs[rb * 64 + ((g8 ^ (rb & 7)) * 8)]);
      }
    }
    #pragma unroll
    for (int i = 0; i < 4; ++i)
      #pragma unroll
      for (int j = 0; j < 4; ++j)
        #pragma unroll
        for (int k2 = 0; k2 < 2; ++k2)
          acc[i][j] = __builtin_amdgcn_mfma_f32_16x16x32_bf16(af[i][k2], bb[j][k2], acc[i][j], 0, 0, 0);
    __syncthreads();
  }
  #pragma unroll
  for (int i = 0; i < 4; ++i) {
    #pragma unroll
    for (int r = 0; r < 4; ++r) {
      const int row = bm * 128 + wr + i * 16 + l4 * 4 + r;
      #pragma unroll
      for (int j = 0; j < 4; ++j) {
        const int col = bn * 256 + wc + j * 16 + l15;
        C[(size_t)row * ldc + col] = f2bf(acc[i][j][r]);
      }
    }
  }
}

// ---------- FFN GEMMs: i8 MFMA, BK=128, both-sides XOR swizzle ----------
__global__ __launch_bounds__(512, 2)
void gemm_up_i8(const char* __restrict__ A, const char* __restrict__ Bw, u16* __restrict__ H,
                const float* __restrict__ wsp, const float* __restrict__ xs) {
  const int K = HID_;
  __shared__ __align__(16) char As[128 * 128];
  __shared__ __align__(16) char Gs[128 * 128];
  __shared__ __align__(16) char Vs[128 * 128];
  const int tid = threadIdx.x;
  const int w = tid >> 6, lane = tid & 63;
  const int l15 = lane & 15, l4 = lane >> 4;
  const int wr = (w >> 2) * 64, wc = (w & 3) * 32;
  int id = blockIdx.x;
  const int cpx = (int)gridDim.x >> 3;
  id = (id & 7) * cpx + (id >> 3);
  const int bm = id & 31, bn = id >> 5;
  const char* Ag = A + (size_t)bm * 128 * K;
  const char* Gg = Bw + (size_t)bn * 128 * K;
  const char* Vg = Bw + ((size_t)INTER_ + bn * 128) * K;
  i32x4 ag[4][2] = {}, av[4][2] = {};
  for (int kk = 0; kk < K; kk += 128) {
    #pragma unroll
    for (int p = 0; p < 2; ++p) {
      const int idx = tid + p * 512;
      const int row = idx >> 3, slot = idx & 7;
      const int ss = slot ^ (row & 7);
      gload16(Ag + (size_t)row * K + kk + ss * 16, &As[idx * 16]);
      gload16(Gg + (size_t)row * K + kk + ss * 16, &Gs[idx * 16]);
      gload16(Vg + (size_t)row * K + kk + ss * 16, &Vs[idx * 16]);
    }
    __syncthreads();
    i32x4 af_[4][2], gf_[2][2], vf_[2][2];
    #pragma unroll
    for (int i = 0; i < 4; ++i) {
      const int r = wr + i * 16 + l15;
      #pragma unroll
      for (int k2 = 0; k2 < 2; ++k2) {
        const int j = k2 * 4 + l4;
        af_[i][k2] = *(const i32x4*)&As[r * 128 + ((j ^ (r & 7)) * 16)];
      }
    }
    #pragma unroll
    for (int jj = 0; jj < 2; ++jj) {
      const int r = wc + jj * 16 + l15;
      #pragma unroll
      for (int k2 = 0; k2 < 2; ++k2) {
        const int j = k2 * 4 + l4;
        gf_[jj][k2] = *(const i32x4*)&Gs[r * 128 + ((j ^ (r & 7)) * 16)];
        vf_[jj][k2] = *(const i32x4*)&Vs[r * 128 + ((j ^ (r & 7)) * 16)];
      }
    }
    #pragma unroll
    for (int i = 0; i < 4; ++i)
      #pragma unroll
      for (int jj = 0; jj < 2; ++jj)
        #pragma unroll
        for (int k2 = 0; k2 < 2; ++k2) {
          ag[i][jj] = __builtin_amdgcn_mfma_i32_16x16x64_i8(af_[i][k2], gf_[jj][k2], ag[i][jj], 0, 0, 0);
          av[i][jj] = __builtin_amdgcn_mfma_i32_16x16x64_i8(af_[i][k2], vf_[jj][k2], av[i][jj], 0, 0, 0);
        }
    __syncthreads();
  }
  const float ws0 = wsp[0];
  #pragma unroll
  for (int i = 0; i < 4; ++i) {
    #pragma unroll
    for (int r = 0; r < 4; ++r) {
      const int row = bm * 128 + wr + i * 16 + l4 * 4 + r;
      const float scl = ws0 / xs[row];
      #pragma unroll
      for (int jj = 0; jj < 2; ++jj) {
        const int col = bn * 128 + wc + jj * 16 + l15;
        const float og = (float)ag[i][jj][r] * scl;
        const float ov = (float)av[i][jj][r] * scl;
        const float hv = og * ov / (1.f + expf(-og));  // silu(og)*ov
        H[(size_t)row * INTER_ + col] = f2bf(hv);
      }
    }
  }
}

// down-proj (round-8 proven config): 256 thr, 128x128 tile, grid dim3(16,32) bn-fastest
__global__ __launch_bounds__(256, 2)
void gemm_dn_i8(const char* __restrict__ A, const char* __restrict__ Bw, u16* __restrict__ C,
                const float* __restrict__ wsp, const float* __restrict__ xs) {
  const int N = HID_, K = INTER_;
  __shared__ __align__(16) char As[128 * 128];
  __shared__ __align__(16) char Bs[128 * 128];
  const int tid = threadIdx.x;
  const int wv = tid >> 6, lane = tid & 63;
  const int l15 = lane & 15, l4 = lane >> 4;
  const int wr = (wv >> 1) * 64, wc = (wv & 1) * 64;
  const int bm = blockIdx.y, bn = blockIdx.x;
  const char* Ag = A + (size_t)bm * 128 * K;
  const char* Bg = Bw + (size_t)bn * 128 * K;
  i32x4 acc[4][4] = {};
  for (int kk = 0; kk < K; kk += 128) {
    #pragma unroll
    for (int p = 0; p < 4; ++p) {
      const int idx = tid + p * 256;
      const int row = idx >> 3, slot = idx & 7;
      const int ss = slot ^ (row & 7);
      gload16(Ag + (size_t)row * K + kk + ss * 16, &As[idx * 16]);
      gload16(Bg + (size_t)row * K + kk + ss * 16, &Bs[idx * 16]);
    }
    __syncthreads();
    i32x4 af_[4][2], bb_[4][2];
    #pragma unroll
    for (int i = 0; i < 4; ++i) {
      const int ra = wr + i * 16 + l15;
      const int rb = wc + i * 16 + l15;
      #pragma unroll
      for (int k2 = 0; k2 < 2; ++k2) {
        const int j = k2 * 4 + l4;
        af_[i][k2] = *(const i32x4*)&As[ra * 128 + ((j ^ (ra & 7)) * 16)];
        bb_[i][k2] = *(const i32x4*)&Bs[rb * 128 + ((j ^ (rb & 7)) * 16)];
      }
    }
    #pragma unroll
    for (int i = 0; i < 4; ++i)
      #pragma unroll
      for (int j = 0; j < 4; ++j)
        #pragma unroll
        for (int k2 = 0; k2 < 2; ++k2)
          acc[i][j] = __builtin_amdgcn_mfma_i32_16x16x64_i8(af_[i][k2], bb_[j][k2], acc[i][j], 0, 0, 0);
    __syncthreads();
  }
  const float ws0 = wsp[0];
  #pragma unroll
  for (int i = 0; i < 4; ++i) {
    #pragma unroll
    for (int r = 0; r < 4; ++r) {
      const int row = bm * 128 + wr + i * 16 + l4 * 4 + r;
      const float scl = ws0 / xs[row];
      #pragma unroll
      for (int j = 0; j < 4; ++j) {
        const int col = bn * 128 + wc + j * 16 + l15;
        C[(size_t)row * N + col] = f2bf((float)acc[i][j][r] * scl);
      }
    }
  }
}

// ---------- attention (MFMA); q/k/v are column slices of fused qkv (row stride ldq) ----------
DEV void write_otile(const f32x16 oc, float invl, char* stgB, u16* alocrow,
                     int da, int l31, int hi, int lane) {
  #pragma unroll
  for (int r = 0; r < 16; ++r) {
    const int dl = (r & 3) + 8 * (r >> 2) + 4 * hi;
    *(u16*)(stgB + l31 * 64 + ((dl * 2) ^ ((l31 & 3) << 4))) = f2bf(oc[r] * invl);
  }
  #pragma unroll
  for (int p = 0; p < 2; ++p) {
    const int s = lane >> 1;
    const int d8 = (lane & 1) * 8 + p * 16;
    const uint4 val = *(const uint4*)(stgB + s * 64 + ((d8 * 2) ^ ((s & 3) << 4)));
    *(uint4*)(alocrow + (size_t)s * HD_ + da * 32 + d8) = val;
  }
}

__global__ __launch_bounds__(512)
void attn_local_mfma(const u16* __restrict__ q, const u16* __restrict__ k, const u16* __restrict__ v,
                     u16* __restrict__ aloc, float* __restrict__ Useg, float* __restrict__ yseg, int ldq) {
  __shared__ __align__(16) u16 Ks[512 * 64];
  __shared__ __align__(16) u16 VT[64 * 512];
  __shared__ __align__(16) u16 SP[9216];
  const int bid = blockIdx.x;
  const int c = bid >> 7, bh = bid & 127;
  const int b = bh >> 5, h = bh & 31;
  const int tid = threadIdx.x, w = tid >> 6, lane = tid & 63;
  const int l31 = lane & 31, hi = lane >> 5;
  const size_t rowbase = ((size_t)b * S_ + c * SEG_) * (size_t)ldq + h * HD_;
  const u16* qg = q + rowbase;
  const u16* kg = k + rowbase;
  const u16* vg = v + rowbase;
  char* KsB = (char*)Ks;
  char* VTB = (char*)VT;
  // ---- K staging: global_load_lds, pre-swizzled SOURCE, linear LDS dest ----
  // final layout identical to KsB[t*128 + ((dg*16)^((t&7)<<4))]
  #pragma unroll
  for (int p = 0; p < 8; ++p) {
    const int idx = tid + p * 512;
    const int t = idx >> 3, dg = idx & 7;
    gload16(kg + (size_t)t * ldq + (size_t)((dg ^ (t & 7)) * 8), KsB + idx * 16);
  }
  // ---- V^T staging: 4 rows packed per ds_write_b64 (layout unchanged) ----
  #pragma unroll
  for (int u = 0; u < 2; ++u) {
    const int unit = tid + u * 512;
    const int g2 = unit & 127, dg = unit >> 7;
    const uint4 r0 = *(const uint4*)(vg + (size_t)(4 * g2 + 0) * ldq + dg * 8);
    const uint4 r1 = *(const uint4*)(vg + (size_t)(4 * g2 + 1) * ldq + dg * 8);
    const uint4 r2 = *(const uint4*)(vg + (size_t)(4 * g2 + 2) * ldq + dg * 8);
    const uint4 r3 = *(const uint4*)(vg + (size_t)(4 * g2 + 3) * ldq + dg * 8);
    const u16* e0 = (const u16*)&r0;
    const u16* e1 = (const u16*)&r1;
    const u16* e2 = (const u16*)&r2;
    const u16* e3 = (const u16*)&r3;
    #pragma unroll
    for (int j = 0; j < 8; ++j) {
      const int d = dg * 8 + j;
      uint2 wv2;
      wv2.x = (u32)e0[j] | ((u32)e1[j] << 16);
      wv2.y = (u32)e2[j] | ((u32)e3[j] << 16);
      *(uint2*)(VTB + d * 1024 + ((8 * g2) ^ ((d & 7) << 4))) = wv2;
    }
  }
  // balanced wave->q-tile map: wave w owns tiles {w, 15-w} (17 t-block iters each)
  uint4 qf[2][4];
  #pragma unroll
  for (int qi = 0; qi < 2; ++qi) {
    const int qt = qi == 0 ? w : 15 - w;
    #pragma unroll
    for (int ks = 0; ks < 4; ++ks)
      qf[qi][ks] = *(const uint4*)(qg + (size_t)(qt * 32 + l31) * ldq + ks * 16 + hi * 8);
  }
  __syncthreads();

  const size_t arow = (size_t)(b * NH_ + h) * S_ + c * SEG_;
  const int swzk = (l31 & 7) << 4;
  char* stgB = (char*)SP + w * 2048;
  #pragma unroll
  for (int qi = 0; qi < 2; ++qi) {
    const int qt = qi == 0 ? w : 15 - w;
    f32x16 o0 = {}, o1 = {};
    float m = -3e38f, l = 0.f;
    const int nb = qt + 1;
    for (int tb = 0; tb < nb; ++tb) {
      f32x16 st = {};
      #pragma unroll
      for (int ks = 0; ks < 4; ++ks) {
        const uint4 ka = *(const uint4*)(KsB + (tb * 32 + l31) * 128 + (((ks * 16 + hi * 8) * 2) ^ swzk));
        st = __builtin_amdgcn_mfma_f32_32x32x16_bf16(__builtin_bit_cast(bf16x8, ka),
                                                     __builtin_bit_cast(bf16x8, qf[qi][ks]), st, 0, 0, 0);
      }
      if (tb == nb - 1) {
        #pragma unroll
        for (int r = 0; r < 16; ++r) {
          const int tl = (r & 3) + 8 * (r >> 2) + 4 * hi;
          if (tl > l31) st[r] = -3e38f;
        }
      }
      float tm = st[0];
      #pragma unroll
      for (int r = 1; r < 16; ++r) tm = fmaxf(tm, st[r]);
      tm = fmaxf(tm, __shfl_xor(tm, 32, 64));
      const float mn = fmaxf(m, tm);
      const float fac = __expf((m - mn) * 0.125f);
      float pr[16]; float ps = 0.f;
      #pragma unroll
      for (int r = 0; r < 16; ++r) { pr[r] = __expf((st[r] - mn) * 0.125f); ps += pr[r]; }
      ps += __shfl_xor(ps, 32, 64);
      l = l * fac + ps;
      m = mn;
      #pragma unroll
      for (int r = 0; r < 16; ++r) { o0[r] *= fac; o1[r] *= fac; }
      #pragma unroll
      for (int c2 = 0; c2 < 2; ++c2) {
        const int bi = c2 * 8;
        const u32 a0 = pkbf(pr[bi + 0], pr[bi + 1]);
        const u32 a1 = pkbf(pr[bi + 2], pr[bi + 3]);
        const u32 a2 = pkbf(pr[bi + 4], pr[bi + 5]);
        const u32 a3 = pkbf(pr[bi + 6], pr[bi + 7]);
        const u32 x0 = (u32)__shfl_xor((int)a0, 32, 64);
        const u32 x1 = (u32)__shfl_xor((int)a1, 32, 64);
        const u32 x2 = (u32)__shfl_xor((int)a2, 32, 64);
        const u32 x3 = (u32)__shfl_xor((int)a3, 32, 64);
        uint4 pw;
        pw.x = hi ? x2 : a0;
        pw.y = hi ? x3 : a1;
        pw.z = hi ? a2 : x0;
        pw.w = hi ? a3 : x1;
        const bf16x8 pfr = __builtin_bit_cast(bf16x8, pw);
        const int tO = (tb * 32 + c2 * 16 + hi * 8) * 2;
        const uint4 v0 = *(const uint4*)(VTB + l31 * 1024 + (tO ^ swzk));
        const uint4 v1 = *(const uint4*)(VTB + (32 + l31) * 1024 + (tO ^ swzk));
        o0 = __builtin_amdgcn_mfma_f32_32x32x16_bf16(__builtin_bit_cast(bf16x8, v0), pfr, o0, 0, 0, 0);
        o1 = __builtin_amdgcn_mfma_f32_32x32x16_bf16(__builtin_bit_cast(bf16x8, v1), pfr, o1, 0, 0, 0);
      }
    }
    const float invl = 1.f / l;
    u16* alocrow = aloc + (arow + qt * 32) * HD_;
    write_otile(o0, invl, stgB, alocrow, 0, l31, hi, lane);
    write_otile(o1, invl, stgB, alocrow, 1, l31, hi, lane);
  }

  __syncthreads();
  float* Ured = (float*)SP;
  float* yred = (float*)((char*)SP + 16384);
  for (int i = tid; i < 4096; i += 512) Ured[i] = 0.f;
  yred[tid] = 0.f;
  __syncthreads();
  f32x16 u00 = {}, u01 = {}, u10 = {}, u11 = {};
  float y0 = 0.f, y1 = 0.f;
  #pragma unroll
  for (int kc = 0; kc < 4; ++kc) {
    const int t0 = w * 64 + kc * 16 + hi * 8;
    uint4 af[2];
    #pragma unroll
    for (int da2 = 0; da2 < 2; ++da2) {
      const int d = da2 * 32 + l31;
      u32 wds[4];
      #pragma unroll
      for (int jp = 0; jp < 4; ++jp) {
        const int ta = t0 + jp * 2;
        const int tb2 = ta + 1;
        const float kfa = bf2f(*(const u16*)(KsB + ta * 128 + ((d * 2) ^ ((ta & 7) << 4))));
        const float kfb = bf2f(*(const u16*)(KsB + tb2 * 128 + ((d * 2) ^ ((tb2 & 7) << 4))));
        const float sa = kfa > 0.f ? kfa + 1.f : __expf(kfa);
        const float sb = kfb > 0.f ? kfb + 1.f : __expf(kfb);
        if (da2 == 0) y0 += sa + sb; else y1 += sa + sb;
        wds[jp] = pkbf(sa, sb);
      }
      af[da2].x = wds[0]; af[da2].y = wds[1]; af[da2].z = wds[2]; af[da2].w = wds[3];
    }
    const int tO = t0 * 2;
    const uint4 vb0 = *(const uint4*)(VTB + l31 * 1024 + (tO ^ swzk));
    const uint4 vb1 = *(const uint4*)(VTB + (32 + l31) * 1024 + (tO ^ swzk));
    const bf16x8 a0f = __builtin_bit_cast(bf16x8, af[0]);
    const bf16x8 a1f = __builtin_bit_cast(bf16x8, af[1]);
    const bf16x8 b0f = __builtin_bit_cast(bf16x8, vb0);
    const bf16x8 b1f = __builtin_bit_cast(bf16x8, vb1);
    u00 = __builtin_amdgcn_mfma_f32_32x32x16_bf16(a0f, b0f, u00, 0, 0, 0);
    u01 = __builtin_amdgcn_mfma_f32_32x32x16_bf16(a0f, b1f, u01, 0, 0, 0);
    u10 = __builtin_amdgcn_mfma_f32_32x32x16_bf16(a1f, b0f, u10, 0, 0, 0);
    u11 = __builtin_amdgcn_mfma_f32_32x32x16_bf16(a1f, b1f, u11, 0, 0, 0);
  }
  y0 += __shfl_xor(y0, 32, 64);
  y1 += __shfl_xor(y1, 32, 64);
  if (hi == 0) { yred[w * 64 + l31] = y0; yred[w * 64 + 32 + l31] = y1; }
  for (int ww = 0; ww < 8; ++ww) {
    if (w == ww) {
      #pragma unroll
      for (int r = 0; r < 16; ++r) {
        const int dl = (r & 3) + 8 * (r >> 2) + 4 * hi;
        Ured[dl * 64 + l31]            += u00[r];
        Ured[dl * 64 + 32 + l31]       += u01[r];
        Ured[(32 + dl) * 64 + l31]     += u10[r];
        Ured[(32 + dl) * 64 + 32 + l31]+= u11[r];
      }
    }
    __syncthreads();
  }
  float* Ug = Useg + (size_t)(c * 128 + bh) * 4096;
  for (int i = tid; i < 4096; i += 512) Ug[i] = Ured[i];
  if (tid < 64) {
    float a2 = 0.f;
    #pragma unroll
    for (int ww = 0; ww < 8; ++ww) a2 += yred[ww * 64 + tid];
    yseg[(size_t)(c * 128 + bh) * 64 + tid] = a2;
  }
}

__global__ __launch_bounds__(256)
void attn_prefix(const float* __restrict__ Useg, const float* __restrict__ yseg,
                 float* __restrict__ Mpre, float* __restrict__ zpre) {
  const int bh = blockIdx.x, tid = threadIdx.x;
  for (int idx = tid; idx < 4096; idx += 256) {
    float a2 = 0.f;
    #pragma unroll
    for (int c = 0; c < 8; ++c) {
      const size_t o = ((size_t)(c * 128 + bh)) * 4096 + idx;
      Mpre[o] = a2;
      a2 += Useg[o];
    }
  }
  if (tid < 64) {
    float a2 = 0.f;
    #pragma unroll
    for (int c = 0; c < 8; ++c) {
      const size_t o = ((size_t)(c * 128 + bh)) * 64 + tid;
      zpre[o] = a2;
      a2 += yseg[o];
    }
  }
}

__global__ __launch_bounds__(512)
void attn_combine(const u16* __restrict__ q, const u16* __restrict__ aloc,
                  const float* __restrict__ Mpre, const float* __restrict__ zpre,
                  const float* __restrict__ beta, u16* __restrict__ attno, int ldq) {
  __shared__ __align__(16) u16 MbT[64 * 64];
  __shared__ float z_lds[64];
  __shared__ float amem[8][16 * 65];
  const int bid = blockIdx.x;
  const int c = bid >> 7, bh = bid & 127;
  const int b = bh >> 5, h = bh & 31;
  const int tid = threadIdx.x, w = tid >> 6, lane = tid & 63;
  const int l15 = lane & 15, l4 = lane >> 4;
  const size_t pre = (size_t)(c * 128 + bh);
  char* MbB = (char*)MbT;
  for (int i = tid; i < 4096; i += 512) {
    const int d = i >> 6, e = i & 63;
    *(u16*)(MbB + (((e * 64 + d) * 2) ^ ((e & 7) << 4))) = f2bf(Mpre[pre * 4096 + i]);
  }
  if (tid < 64) z_lds[tid] = zpre[pre * 64 + tid];
  __syncthreads();
  bf16x8 bb[2][4];
  #pragma unroll
  for (int ks = 0; ks < 2; ++ks)
    #pragma unroll
    for (int jt = 0; jt < 4; ++jt) {
      const int e = jt * 16 + l15;
      const uint4 u = *(const uint4*)(MbB + (((e * 64 + ks * 32 + l4 * 8) * 2) ^ ((e & 7) << 4)));
      bb[ks][jt] = __builtin_bit_cast(bf16x8, u);
    }
  const float g = sigmoidf_(beta[h]);
  const float og = 1.f - g;
  const u16* qg = q + ((size_t)b * S_ + c * SEG_) * ldq + h * HD_;
  const size_t arow = (size_t)(b * NH_ + h) * S_ + c * SEG_;
  u16* orow = attno + ((size_t)b * S_ + c * SEG_) * HID_ + h * HD_;
  const int rr = lane >> 2, cq = (lane & 3) * 16;
  #pragma unroll
  for (int mi = 0; mi < 4; ++mi) {
    const int s0 = w * 64 + mi * 16;
    f32x4 acc[4] = {};
    float pd = 0.f;
    #pragma unroll
    for (int ks = 0; ks < 2; ++ks) {
      const uint4 qv = *(const uint4*)(qg + (size_t)(s0 + l15) * ldq + ks * 32 + l4 * 8);
      float f[8]; bf8tof(qv, f);
      float sq[8];
      #pragma unroll
      for (int j = 0; j < 8; ++j) {
        sq[j] = f[j] > 0.f ? f[j] + 1.f : __expf(f[j]);
        pd = fmaf(sq[j], z_lds[ks * 32 + l4 * 8 + j], pd);
      }
      uint4 pw;
      pw.x = pkbf(sq[0], sq[1]); pw.y = pkbf(sq[2], sq[3]);
      pw.z = pkbf(sq[4], sq[5]); pw.w = pkbf(sq[6], sq[7]);
      const bf16x8 af = __builtin_bit_cast(bf16x8, pw);
      #pragma unroll
      for (int jt = 0; jt < 4; ++jt)
        acc[jt] = __builtin_amdgcn_mfma_f32_16x16x32_bf16(af, bb[ks][jt], acc[jt], 0, 0, 0);
    }
    pd += __shfl_xor(pd, 16, 64);
    pd += __shfl_xor(pd, 32, 64);
    pd += 1e-6f;
    float dinv[4];
    #pragma unroll
    for (int r = 0; r < 4; ++r) dinv[r] = 1.f / __shfl(pd, l4 * 4 + r, 64);
    #pragma unroll
    for (int jt = 0; jt < 4; ++jt)
      #pragma unroll
      for (int r = 0; r < 4; ++r)
        amem[w][(l4 * 4 + r) * 65 + jt * 16 + l15] = acc[jt][r] * dinv[r];
    const int s = s0 + rr;
    const u16* alr = aloc + (arow + s) * HD_ + cq;
    const uint4 a0 = *(const uint4*)alr;
    const uint4 a1 = *(const uint4*)(alr + 8);
    float alf[16];
    bf8tof(a0, alf); bf8tof(a1, alf + 8);
    float ov[16];
    #pragma unroll
    for (int t = 0; t < 16; ++t)
      ov[t] = g * amem[w][rr * 65 + cq + t] + og * alf[t];
    *(uint4*)(orow + (size_t)s * HID_ + cq) = f8tobf(ov);
    *(uint4*)(orow + (size_t)s * HID_ + cq + 8) = f8tobf(ov + 8);
  }
}

// ---------- launch ----------
extern "C" void kernel_launch(void* const* d_in, const int* in_sizes, int n_in,
                              void* d_out, int out_size, void* d_ws, size_t ws_size,
                              hipStream_t stream) {
  const float* x    = (const float*)d_in[0];
  const float* wq   = (const float*)d_in[1];
  const float* wk   = (const float*)d_in[2];
  const float* wv   = (const float*)d_in[3];
  const float* wo   = (const float*)d_in[4];
  const float* beta = (const float*)d_in[5];
  const float* gate = (const float*)d_in[6];
  const float* anw  = (const float*)d_in[7];
  const float* mnw  = (const float*)d_in[8];
  const float* arnw = (const float*)d_in[9];
  const float* arsc = (const float*)d_in[10];
  const float* mrnw = (const float*)d_in[11];
  const float* mrsc = (const float*)d_in[12];
  const float* fup  = (const float*)d_in[13];
  const float* fdn  = (const float*)d_in[14];

  char* W = (char*)d_ws;
  const size_t MB = 1ull << 20;
  u16*   xn1   = (u16*)(W + 0);
  u16*   attno = (u16*)(W + 0);
  u16*   mlpb  = (u16*)(W + 0);
  u16*   qkv   = (u16*)(W + 64 * MB);
  char*  xq1   = (char*)(W + 64 * MB);
  u16*   aob   = (u16*)(W + 128 * MB);
  u16*   hbuf  = (u16*)(W + 128 * MB);
  u16*   alocb = (u16*)(W + 256 * MB);
  float* x2    = (float*)(W + 192 * MB);
  float* Useg  = (float*)(W + 320 * MB);
  float* Mpre  = (float*)(W + 336 * MB);
  float* yseg  = (float*)(W + 352 * MB);
  float* zpre  = (float*)(W + 352 * MB + 262144);
  float* xs1   = (float*)(W + 352 * MB + 524288);
  float* xs2   = (float*)(W + 352 * MB + 589824);
  float* wsu   = (float*)(W + 352 * MB + 655360);
  float* wsd   = (float*)(W + 352 * MB + 655616);
  float* partU = (float*)(W + 352 * MB + 655872);
  float* partD = (float*)(W + 352 * MB + 664064);
  u16*   w16qkv= (u16*)(W + 353 * MB);          // [6144,2048] = wq|wk|wv
  u16*   w16o  = (u16*)(W + 377 * MB);
  char*  wqup  = (char*)(W + 385 * MB);
  char*  wqdn  = (char*)(W + 417 * MB);
  char*  hq    = (char*)(W + 433 * MB);

  // weight prep
  castf2b<<<4096, 256, 0, stream>>>(wq, w16qkv);
  castf2b<<<4096, 256, 0, stream>>>(wk, w16qkv + (size_t)HID_ * HID_);
  castf2b<<<4096, 256, 0, stream>>>(wv, w16qkv + 2 * (size_t)HID_ * HID_);
  castf2b<<<4096, 256, 0, stream>>>(wo, w16o);
  absmean_part<<<2048, 256, 0, stream>>>(fup, partU);
  absmean_part<<<1024, 256, 0, stream>>>(fdn, partD);
  absmean_fin<<<1, 256, 0, stream>>>(partU, 2048, 1.f / 33554432.f, wsu);
  absmean_fin<<<1, 256, 0, stream>>>(partD, 1024, 1.f / 16777216.f, wsd);
  ternarize_i8<<<32768, 256, 0, stream>>>(fup, wsu, wqup);
  ternarize_i8<<<16384, 256, 0, stream>>>(fdn, wsd, wqdn);

  // attention path: fused QKV GEMM -> qkv[16384,6144]
  rmsnorm_cast<<<16384, 256, 0, stream>>>(x, anw, xn1);
  gemm_bt2<24><<<3072, 512, 0, stream>>>(xn1, w16qkv, qkv, HID_, LDQ_);
  attn_local_mfma<<<1024, 512, 0, stream>>>(qkv, qkv + HID_, qkv + 2 * HID_, alocb, Useg, yseg, LDQ_);
  attn_prefix<<<128, 256, 0, stream>>>(Useg, yseg, Mpre, zpre);
  attn_combine<<<1024, 512, 0, stream>>>(qkv, alocb, Mpre, zpre, beta, attno, LDQ_);
  gemm_bt2<8><<<1024, 512, 0, stream>>>(attno, w16o, aob, HID_, HID_);
  resid1_rms2<<<16384, 256, 0, stream>>>(x, aob, gate, arnw, arsc, mnw, x2, xq1, xs1);

  // MLP path (4 token-chunks of 4096 rows, i8 MFMA)
  for (int cc = 0; cc < 4; ++cc) {
    const size_t base = (size_t)cc * CHROWS_;
    gemm_up_i8<<<2048, 512, 0, stream>>>(xq1 + base * HID_, wqup, hbuf, wsu, xs1 + base);
    quant_h_i8<<<4096, 256, 0, stream>>>(hbuf, hq, xs2 + base);
    gemm_dn_i8<<<dim3(16, 32), 256, 0, stream>>>(hq, wqdn, mlpb + base * HID_, wsd, xs2 + base);
  }
  final_resid<<<16384, 256, 0, stream>>>(x2, mlpb, mrnw, mrsc, (float*)d_out);
}